// Round 3
// baseline (250.176 us; speedup 1.0000x reference)
//
#include <hip/hip_runtime.h>
#include <math.h>

// Problem constants (SemanticAwareTransitions_9826885173968)
#define V_  512
#define D_  256
#define H_  8
#define DH_ 32
#define FF_ 2048
#define L_  2
#define B_  4
#define S_  128
#define T_  (B_*S_)   // 512 tokens

typedef float f32x4 __attribute__((ext_vector_type(4)));
typedef short s16x8 __attribute__((ext_vector_type(8)));
typedef unsigned short u16x4 __attribute__((ext_vector_type(4)));
typedef unsigned short ushort_t;

// fp32 -> bf16 bits, round-to-nearest-even
__device__ __forceinline__ ushort_t f2b(float f) {
    unsigned int u = __builtin_bit_cast(unsigned int, f);
    u += 0x7FFFu + ((u >> 16) & 1u);
    return (ushort_t)(u >> 16);
}
__device__ __forceinline__ float b2f(ushort_t h) {
    unsigned int u = ((unsigned int)h) << 16;
    return __builtin_bit_cast(float, u);
}

__device__ __forceinline__ float waveReduceSum(float v) {
#pragma unroll
    for (int off = 32; off > 0; off >>= 1) v += __shfl_xor(v, off);
    return v;
}
__device__ __forceinline__ float waveReduceMax(float v) {
#pragma unroll
    for (int off = 32; off > 0; off >>= 1) v = fmaxf(v, __shfl_xor(v, off));
    return v;
}

// ---------------------------------------------------------------------------
// bf16 MFMA GEMM (64x64 tile, BK=32, 4 waves). Used for QKV and W1.
// mfma_f32_16x16x32_bf16 D-layout: col=lane&15, row=(lane>>4)*4+reg.
// ---------------------------------------------------------------------------
template<int RELU, int OUTB, int BIAS>
__device__ __forceinline__ void mgemm_body(
    const ushort_t* __restrict__ A, const ushort_t* __restrict__ BT,
    const float* __restrict__ bias, float* __restrict__ Cf,
    ushort_t* __restrict__ Cb, int M, int N, int K, int kBegin, int kSteps)
{
    __shared__ ushort_t Al[64][40];
    __shared__ ushort_t Bl[64][40];
    const int tid  = threadIdx.x;
    const int m0   = blockIdx.y * 64, n0 = blockIdx.x * 64;
    const int lane = tid & 63, w = tid >> 6;
    const int srow = tid >> 2, sseg = (tid & 3) * 8;
    const int l15  = lane & 15,  kg = (lane >> 4) * 8;

    f32x4 acc0 = {0.f,0.f,0.f,0.f}, acc1 = acc0, acc2 = acc0, acc3 = acc0;

    for (int kt = 0; kt < kSteps; ++kt) {
        const int k0 = kBegin + kt * 32;
        s16x8 av = *(const s16x8*)&A [(size_t)(m0 + srow) * K + k0 + sseg];
        s16x8 bv = *(const s16x8*)&BT[(size_t)(n0 + srow) * K + k0 + sseg];
        __syncthreads();
        *(s16x8*)&Al[srow][sseg] = av;
        *(s16x8*)&Bl[srow][sseg] = bv;
        __syncthreads();
        s16x8 bfr = *(const s16x8*)&Bl[w * 16 + l15][kg];
        s16x8 a0  = *(const s16x8*)&Al[     l15][kg];
        s16x8 a1  = *(const s16x8*)&Al[16 + l15][kg];
        s16x8 a2  = *(const s16x8*)&Al[32 + l15][kg];
        s16x8 a3  = *(const s16x8*)&Al[48 + l15][kg];
        acc0 = __builtin_amdgcn_mfma_f32_16x16x32_bf16(a0, bfr, acc0, 0, 0, 0);
        acc1 = __builtin_amdgcn_mfma_f32_16x16x32_bf16(a1, bfr, acc1, 0, 0, 0);
        acc2 = __builtin_amdgcn_mfma_f32_16x16x32_bf16(a2, bfr, acc2, 0, 0, 0);
        acc3 = __builtin_amdgcn_mfma_f32_16x16x32_bf16(a3, bfr, acc3, 0, 0, 0);
    }

    const int col = n0 + w * 16 + l15;
    const float bb = BIAS ? bias[col] : 0.f;
    f32x4 accs[4] = {acc0, acc1, acc2, acc3};
#pragma unroll
    for (int r = 0; r < 4; ++r) {
#pragma unroll
        for (int e = 0; e < 4; ++e) {
            const int row = m0 + r * 16 + (lane >> 4) * 4 + e;
            float v = accs[r][e] + bb;
            if (RELU) v = fmaxf(v, 0.f);
            if (OUTB) Cb[(size_t)row * N + col] = f2b(v);
            else      Cf[(size_t)row * N + col] = v;
        }
    }
}

template<int RELU, int OUTB, int BIAS>
__global__ __launch_bounds__(256) void mgemm_k(const ushort_t* A, const ushort_t* BT,
    const float* bias, float* Cf, ushort_t* Cb, int M, int N, int K, int kChunk)
{
    const int z = blockIdx.z;
    mgemm_body<RELU, OUTB, BIAS>(A, BT, bias,
        Cf ? Cf + (size_t)z * M * N : nullptr, Cb, M, N, K, z * kChunk, kChunk / 32);
}

__global__ __launch_bounds__(256) void qkv_k(const ushort_t* Xb, const ushort_t* WT,
    const float* bq, const float* bk, const float* bv,
    ushort_t* Qb, ushort_t* Kb, ushort_t* Vb)
{
    const int z = blockIdx.z;
    const ushort_t* bt = WT + (size_t)z * (D_ * D_);
    const float* bias; ushort_t* out;
    if (z == 0)      { bias = bq; out = Qb; }
    else if (z == 1) { bias = bk; out = Kb; }
    else             { bias = bv; out = Vb; }
    mgemm_body<0, 1, 1>(Xb, bt, bias, nullptr, out, T_, D_, D_, 0, D_ / 32);
}

// ---------------------------------------------------------------------------
// prep: blocks [0,512) = embedding gather (+bf16 X and emb); [512,3072) =
// weight transpose fp32 [R][C] -> bf16 [C][R] in 32x32 LDS tiles.
// ---------------------------------------------------------------------------
__global__ __launch_bounds__(256) void prep_k(const int* __restrict__ xt,
    const float* __restrict__ emb, float* __restrict__ X,
    ushort_t* __restrict__ Xb, ushort_t* __restrict__ embB,
    const float* __restrict__ Wq, const float* __restrict__ Wk,
    const float* __restrict__ Wv, const float* __restrict__ Wo,
    const float* __restrict__ W1, const float* __restrict__ W2,
    ushort_t* __restrict__ WT, ushort_t* __restrict__ W1T, ushort_t* __restrict__ W2T)
{
    __shared__ float Tl[32][33];
    const int tid = threadIdx.x;
    if (blockIdx.x < 512) {
        const int idx = blockIdx.x * 256 + tid;       // < T_*D_ == V_*D_
        const int t = idx >> 8, d = idx & 255;
        const float v = emb[(size_t)xt[t] * D_ + d];
        X[idx]  = v;
        Xb[idx] = f2b(v);
        embB[idx] = f2b(emb[idx]);
        return;
    }
    const int id = blockIdx.x - 512;
    const int l  = id >= 1280 ? 1 : 0;
    const int t  = id - l * 1280;
    const float* src; ushort_t* dst; int R, C, rt, ct;
    if (t < 256) {
        const int kind = t >> 6, tl = t & 63;
        const float* s0 = (kind == 0) ? Wq : (kind == 1) ? Wk : (kind == 2) ? Wv : Wo;
        src = s0 + (size_t)l * (D_ * D_);
        dst = WT + (size_t)l * (4 * D_ * D_) + (size_t)kind * (D_ * D_);
        R = D_; C = D_; rt = tl >> 3; ct = tl & 7;
    } else if (t < 768) {
        const int tl = t - 256;
        src = W1 + (size_t)l * (D_ * FF_); dst = W1T + (size_t)l * (D_ * FF_);
        R = D_; C = FF_; rt = tl >> 6; ct = tl & 63;
    } else {
        const int tl = t - 768;
        src = W2 + (size_t)l * (FF_ * D_); dst = W2T + (size_t)l * (FF_ * D_);
        R = FF_; C = D_; rt = tl >> 3; ct = tl & 7;
    }
    const int r = tid >> 3, c4 = (tid & 7) * 4;
    f32x4 v = *(const f32x4*)&src[(size_t)(rt * 32 + r) * C + ct * 32 + c4];
    Tl[r][c4] = v[0]; Tl[r][c4 + 1] = v[1]; Tl[r][c4 + 2] = v[2]; Tl[r][c4 + 3] = v[3];
    __syncthreads();
    u16x4 ov;
    ov[0] = f2b(Tl[c4 + 0][r]); ov[1] = f2b(Tl[c4 + 1][r]);
    ov[2] = f2b(Tl[c4 + 2][r]); ov[3] = f2b(Tl[c4 + 3][r]);
    *(u16x4*)&dst[(size_t)(ct * 32 + r) * R + rt * 32 + c4] = ov;
}

// ---------------------------------------------------------------------------
// Fused attention: one block per (b,h,q-quarter). fp32 math, bf16 I/O.
// ---------------------------------------------------------------------------
__global__ __launch_bounds__(256) void attn_k(const ushort_t* __restrict__ Qb,
    const ushort_t* __restrict__ Kb, const ushort_t* __restrict__ Vb,
    ushort_t* __restrict__ Ob)
{
    __shared__ float Qs[32][36], Ks[128][36], Vs[128][36], Ps[32][132];
    const int bh = blockIdx.x, b = bh >> 3, h = bh & 7;
    const int i0 = blockIdx.y * 32;
    const int tid = threadIdx.x;

#pragma unroll
    for (int it = 0; it < 2; ++it) {                 // K,V: 512 8-elem chunks
        const int g = it * 256 + tid;
        const int r = g >> 2, c8 = (g & 3) * 8;
        s16x8 kv = *(const s16x8*)&Kb[(size_t)(b * S_ + r) * D_ + h * DH_ + c8];
        s16x8 vv = *(const s16x8*)&Vb[(size_t)(b * S_ + r) * D_ + h * DH_ + c8];
        f32x4 klo = {b2f((ushort_t)kv[0]), b2f((ushort_t)kv[1]), b2f((ushort_t)kv[2]), b2f((ushort_t)kv[3])};
        f32x4 khi = {b2f((ushort_t)kv[4]), b2f((ushort_t)kv[5]), b2f((ushort_t)kv[6]), b2f((ushort_t)kv[7])};
        f32x4 vlo = {b2f((ushort_t)vv[0]), b2f((ushort_t)vv[1]), b2f((ushort_t)vv[2]), b2f((ushort_t)vv[3])};
        f32x4 vhi = {b2f((ushort_t)vv[4]), b2f((ushort_t)vv[5]), b2f((ushort_t)vv[6]), b2f((ushort_t)vv[7])};
        *(f32x4*)&Ks[r][c8]     = klo;  *(f32x4*)&Ks[r][c8 + 4] = khi;
        *(f32x4*)&Vs[r][c8]     = vlo;  *(f32x4*)&Vs[r][c8 + 4] = vhi;
    }
    if (tid < 128) {                                  // Q: 128 chunks
        const int r = tid >> 2, c8 = (tid & 3) * 8;
        s16x8 qv = *(const s16x8*)&Qb[(size_t)(b * S_ + i0 + r) * D_ + h * DH_ + c8];
        f32x4 qlo = {b2f((ushort_t)qv[0]), b2f((ushort_t)qv[1]), b2f((ushort_t)qv[2]), b2f((ushort_t)qv[3])};
        f32x4 qhi = {b2f((ushort_t)qv[4]), b2f((ushort_t)qv[5]), b2f((ushort_t)qv[6]), b2f((ushort_t)qv[7])};
        *(f32x4*)&Qs[r][c8] = qlo;  *(f32x4*)&Qs[r][c8 + 4] = qhi;
    }
    __syncthreads();

    const int i = tid >> 3, jg = tid & 7;
    const float sc = 0.17677669529663687f;   // 1/sqrt(32)
    float sv[16];
    float mx = -1e30f;
#pragma unroll
    for (int jj = 0; jj < 16; ++jj) {
        const int j = jg + jj * 8;
        f32x4 a4 = {0.f,0.f,0.f,0.f};
#pragma unroll
        for (int kk = 0; kk < 8; ++kk) {
            f32x4 q = *(const f32x4*)&Qs[i][kk * 4];
            f32x4 k = *(const f32x4*)&Ks[j][kk * 4];
            a4 += q * k;
        }
        const float sdot = (a4[0] + a4[1] + a4[2] + a4[3]) * sc;
        sv[jj] = sdot;
        mx = fmaxf(mx, sdot);
    }
    mx = fmaxf(mx, __shfl_xor(mx, 1));
    mx = fmaxf(mx, __shfl_xor(mx, 2));
    mx = fmaxf(mx, __shfl_xor(mx, 4));
    float sum = 0.f;
#pragma unroll
    for (int jj = 0; jj < 16; ++jj) {
        const float e = __expf(sv[jj] - mx);
        Ps[i][jg + jj * 8] = e;
        sum += e;
    }
    sum += __shfl_xor(sum, 1);
    sum += __shfl_xor(sum, 2);
    sum += __shfl_xor(sum, 4);
    const float inv = 1.f / sum;
    __syncthreads();

    const int dg = tid & 7;
    f32x4 o = {0.f,0.f,0.f,0.f};
#pragma unroll 4
    for (int j = 0; j < 128; ++j) {
        const float p = Ps[i][j];
        f32x4 vv = *(const f32x4*)&Vs[j][dg * 4];
        o += vv * p;
    }
    u16x4 ov;
    ov[0] = f2b(o[0] * inv); ov[1] = f2b(o[1] * inv);
    ov[2] = f2b(o[2] * inv); ov[3] = f2b(o[3] * inv);
    *(u16x4*)&Ob[(size_t)(b * S_ + i0 + i) * D_ + h * DH_ + dg * 4] = ov;
}

// ---------------------------------------------------------------------------
// woln: x = LN(x + A@Wo^T + bo)*s + b.  16 blocks (M-tile 32), 256 thr.
// Full-width N=256 tile so LN is block-local. K=256, 8 k-steps.
// ---------------------------------------------------------------------------
__global__ __launch_bounds__(256) void woln_k(
    const ushort_t* __restrict__ A, const ushort_t* __restrict__ BT,
    const float* __restrict__ bias, float* __restrict__ X,
    ushort_t* __restrict__ Xb, const float* __restrict__ lns,
    const float* __restrict__ lnb)
{
    __shared__ ushort_t As[32][40];
    __shared__ ushort_t Bs[256][40];
    __shared__ float Ct[32][272];
    const int tid = threadIdx.x;
    const int m0 = blockIdx.x * 32;
    const int w = tid >> 6, lane = tid & 63;
    const int l15 = lane & 15, kgrp = (lane >> 4) * 8;

    f32x4 acc[2][4] = {};
    const int ar = tid >> 2, aseg = tid & 3;          // A: threads < 128

    for (int t = 0; t < 8; ++t) {
        const int k0 = t * 32;
        s16x8 av;
        if (tid < 128) av = *(const s16x8*)&A[(size_t)(m0 + ar) * D_ + k0 + aseg * 8];
        s16x8 bv[4];
#pragma unroll
        for (int i = 0; i < 4; ++i) {
            const int c = tid + i * 256;
            bv[i] = *(const s16x8*)&BT[(size_t)(c >> 2) * D_ + k0 + (c & 3) * 8];
        }
        __syncthreads();
        if (tid < 128) *(s16x8*)&As[ar][aseg * 8] = av;
#pragma unroll
        for (int i = 0; i < 4; ++i) {
            const int c = tid + i * 256;
            *(s16x8*)&Bs[c >> 2][(c & 3) * 8] = bv[i];
        }
        __syncthreads();
        s16x8 bf[4], af[2];
#pragma unroll
        for (int j = 0; j < 4; ++j) bf[j] = *(const s16x8*)&Bs[w * 64 + j * 16 + l15][kgrp];
#pragma unroll
        for (int r = 0; r < 2; ++r) af[r] = *(const s16x8*)&As[r * 16 + l15][kgrp];
#pragma unroll
        for (int r = 0; r < 2; ++r)
#pragma unroll
            for (int j = 0; j < 4; ++j)
                acc[r][j] = __builtin_amdgcn_mfma_f32_16x16x32_bf16(af[r], bf[j], acc[r][j], 0, 0, 0);
    }
    __syncthreads();
#pragma unroll
    for (int r = 0; r < 2; ++r)
#pragma unroll
        for (int j = 0; j < 4; ++j)
#pragma unroll
            for (int e = 0; e < 4; ++e)
                Ct[r * 16 + (lane >> 4) * 4 + e][w * 64 + j * 16 + l15] = acc[r][j][e];
    __syncthreads();

    // LN: 8 threads per row, 32 cols each
    const int row = tid >> 3, c0 = (tid & 7) * 32;
    const int grow = m0 + row;
    float a[32];
    float sum = 0.f;
#pragma unroll
    for (int c = 0; c < 32; ++c) {
        a[c] = Ct[row][c0 + c] + X[(size_t)grow * D_ + c0 + c] + bias[c0 + c];
        sum += a[c];
    }
    sum += __shfl_xor(sum, 1); sum += __shfl_xor(sum, 2); sum += __shfl_xor(sum, 4);
    const float mean = sum * (1.f / D_);
    float vs = 0.f;
#pragma unroll
    for (int c = 0; c < 32; ++c) { const float d = a[c] - mean; vs += d * d; }
    vs += __shfl_xor(vs, 1); vs += __shfl_xor(vs, 2); vs += __shfl_xor(vs, 4);
    const float rstd = rsqrtf(vs * (1.f / D_) + 1e-5f);
#pragma unroll
    for (int c4 = 0; c4 < 8; ++c4) {
        f32x4 y4; u16x4 yb;
#pragma unroll
        for (int e = 0; e < 4; ++e) {
            const int c = c4 * 4 + e;
            const float y = (a[c] - mean) * rstd * lns[c0 + c] + lnb[c0 + c];
            y4[e] = y; yb[e] = f2b(y);
        }
        *(f32x4*)&X [(size_t)grow * D_ + c0 + c4 * 4] = y4;
        *(u16x4*)&Xb[(size_t)grow * D_ + c0 + c4 * 4] = yb;
    }
}

// ---------------------------------------------------------------------------
// w2ln: x = LN(x + A@W2^T + b2)*s + b.  16 blocks (M-tile 32), 512 thr =
// 8 waves = 2 K-groups x 4 N-groups; K=2048 -> 32 steps of 32 per K-group.
// LDS: staging (46KB) union'd with the fp32 C tile (35KB).
// ---------------------------------------------------------------------------
__global__ __launch_bounds__(512) void w2ln_k(
    const ushort_t* __restrict__ A, const ushort_t* __restrict__ BT,
    const float* __restrict__ bias, float* __restrict__ X,
    ushort_t* __restrict__ Xb, const float* __restrict__ lns,
    const float* __restrict__ lnb)
{
    __shared__ __align__(16) char ubuf[46080];
    ushort_t (*As)[40] = (ushort_t (*)[40])ubuf;            // [64][40]  (kg*32+r)
    ushort_t (*Bs)[40] = (ushort_t (*)[40])(ubuf + 5120);   // [512][40] (kg*256+r)
    float    (*Ct)[272] = (float (*)[272])ubuf;             // [32][272] (after K loop)

    const int tid = threadIdx.x;
    const int m0 = blockIdx.x * 32;
    const int w = tid >> 6, lane = tid & 63;
    const int kg = w >> 2, ng = w & 3;
    const int l15 = lane & 15, kgrp = (lane >> 4) * 8;

    f32x4 acc[2][4] = {};
    const int akg = tid >> 7, arr = (tid >> 2) & 31, aseg = tid & 3;   // tid<256

    for (int t = 0; t < 32; ++t) {
        s16x8 av, bv[4];
        if (tid < 256)
            av = *(const s16x8*)&A[(size_t)(m0 + arr) * FF_ + akg * 1024 + t * 32 + aseg * 8];
#pragma unroll
        for (int i = 0; i < 4; ++i) {
            const int c = tid + i * 512;
            const int bkg = c >> 10, br = (c >> 2) & 255, bseg = c & 3;
            bv[i] = *(const s16x8*)&BT[(size_t)br * FF_ + bkg * 1024 + t * 32 + bseg * 8];
        }
        __syncthreads();
        if (tid < 256) *(s16x8*)&As[akg * 32 + arr][aseg * 8] = av;
#pragma unroll
        for (int i = 0; i < 4; ++i) {
            const int c = tid + i * 512;
            const int bkg = c >> 10, br = (c >> 2) & 255, bseg = c & 3;
            *(s16x8*)&Bs[bkg * 256 + br][bseg * 8] = bv[i];
        }
        __syncthreads();
        s16x8 bf[4], af[2];
#pragma unroll
        for (int j = 0; j < 4; ++j) bf[j] = *(const s16x8*)&Bs[kg * 256 + ng * 64 + j * 16 + l15][kgrp];
#pragma unroll
        for (int r = 0; r < 2; ++r) af[r] = *(const s16x8*)&As[kg * 32 + r * 16 + l15][kgrp];
#pragma unroll
        for (int r = 0; r < 2; ++r)
#pragma unroll
            for (int j = 0; j < 4; ++j)
                acc[r][j] = __builtin_amdgcn_mfma_f32_16x16x32_bf16(af[r], bf[j], acc[r][j], 0, 0, 0);
    }
    __syncthreads();                     // staging dead; Ct takes over the LDS
    if (kg == 0) {
#pragma unroll
        for (int r = 0; r < 2; ++r)
#pragma unroll
            for (int j = 0; j < 4; ++j)
#pragma unroll
                for (int e = 0; e < 4; ++e)
                    Ct[r * 16 + (lane >> 4) * 4 + e][ng * 64 + j * 16 + l15] = acc[r][j][e];
    }
    __syncthreads();
    if (kg == 1) {
#pragma unroll
        for (int r = 0; r < 2; ++r)
#pragma unroll
            for (int j = 0; j < 4; ++j)
#pragma unroll
                for (int e = 0; e < 4; ++e)
                    Ct[r * 16 + (lane >> 4) * 4 + e][ng * 64 + j * 16 + l15] += acc[r][j][e];
    }
    __syncthreads();

    // LN: 16 threads per row, 16 cols each
    const int row = tid >> 4, c0 = (tid & 15) * 16;
    const int grow = m0 + row;
    float a[16];
    float sum = 0.f;
#pragma unroll
    for (int c = 0; c < 16; ++c) {
        a[c] = Ct[row][c0 + c] + X[(size_t)grow * D_ + c0 + c] + bias[c0 + c];
        sum += a[c];
    }
    sum += __shfl_xor(sum, 1); sum += __shfl_xor(sum, 2);
    sum += __shfl_xor(sum, 4); sum += __shfl_xor(sum, 8);
    const float mean = sum * (1.f / D_);
    float vs = 0.f;
#pragma unroll
    for (int c = 0; c < 16; ++c) { const float d = a[c] - mean; vs += d * d; }
    vs += __shfl_xor(vs, 1); vs += __shfl_xor(vs, 2);
    vs += __shfl_xor(vs, 4); vs += __shfl_xor(vs, 8);
    const float rstd = rsqrtf(vs * (1.f / D_) + 1e-5f);
#pragma unroll
    for (int c4 = 0; c4 < 4; ++c4) {
        f32x4 y4; u16x4 yb;
#pragma unroll
        for (int e = 0; e < 4; ++e) {
            const int c = c4 * 4 + e;
            const float y = (a[c] - mean) * rstd * lns[c0 + c] + lnb[c0 + c];
            y4[e] = y; yb[e] = f2b(y);
        }
        *(f32x4*)&X [(size_t)grow * D_ + c0 + c4 * 4] = y4;
        *(u16x4*)&Xb[(size_t)grow * D_ + c0 + c4 * 4] = yb;
    }
}

// ---------------------------------------------------------------------------
// Fused logits + softmax + broadcast. One block per token t (512 blocks).
// Thread computes 2 logit cols by fp32 dot (embB L2-resident), block softmax,
// then streams 512 identical rows (1MB) with nontemporal float4 stores.
// ---------------------------------------------------------------------------
__global__ __launch_bounds__(256) void bcast_k(const ushort_t* __restrict__ Xb,
    const ushort_t* __restrict__ embB, const float* __restrict__ temp,
    float* __restrict__ out)
{
    __shared__ float xrow[D_];
    __shared__ float row[V_];
    __shared__ float red[4];
    const int t = blockIdx.x, tid = threadIdx.x;
    xrow[tid] = b2f(Xb[(size_t)t * D_ + tid]);
    __syncthreads();

    const float rT = 1.f / temp[0];
    float l0 = 0.f, l1 = 0.f;
    {
        const ushort_t* e0p = &embB[(size_t)tid * D_];
        const ushort_t* e1p = &embB[(size_t)(tid + 256) * D_];
#pragma unroll 8
        for (int cc = 0; cc < 32; ++cc) {
            s16x8 a0 = *(const s16x8*)&e0p[cc * 8];
            s16x8 a1 = *(const s16x8*)&e1p[cc * 8];
#pragma unroll
            for (int e = 0; e < 8; ++e) {
                const float xe = xrow[cc * 8 + e];
                l0 = fmaf(xe, b2f((ushort_t)a0[e]), l0);
                l1 = fmaf(xe, b2f((ushort_t)a1[e]), l1);
            }
        }
        l0 *= rT; l1 *= rT;
    }
    float m = waveReduceMax(fmaxf(l0, l1));
    if ((tid & 63) == 0) red[tid >> 6] = m;
    __syncthreads();
    m = fmaxf(fmaxf(red[0], red[1]), fmaxf(red[2], red[3]));
    __syncthreads();
    const float e0 = __expf(l0 - m), e1 = __expf(l1 - m);
    float s = waveReduceSum(e0 + e1);
    if ((tid & 63) == 0) red[tid >> 6] = s;
    __syncthreads();
    const float inv = 1.f / (red[0] + red[1] + red[2] + red[3]);
    row[tid]       = e0 * inv;
    row[tid + 256] = e1 * inv;
    __syncthreads();

    const int c = tid & 127, rh = tid >> 7;
    f32x4 v4 = *(const f32x4*)&row[c * 4];
    f32x4* dst = (f32x4*)out + (size_t)t * V_ * (V_ / 4);
#pragma unroll 4
    for (int it = 0; it < 256; ++it) {
        const int i = it * 2 + rh;
        __builtin_nontemporal_store(v4, &dst[(size_t)i * (V_ / 4) + c]);
    }
}

// ---------------------------------------------------------------------------
// Host launch. ws layout (bytes), total 9.0 MB:
//   0        X    fp32 512KB      | 1835008 Ffb  bf16 2MB
//   524288   Qb   bf16 256KB      | 3932160 embB bf16 256KB
//   786432   Kb   bf16 256KB      | 4194304 WT   bf16 1MB
//   1048576  Vb   bf16 256KB      | 5242880 W1T  bf16 2MB
//   1310720  Ob   bf16 256KB      | 7340032 W2T  bf16 2MB -> 9437184
//   1572864  Xb   bf16 256KB
// ---------------------------------------------------------------------------
extern "C" void kernel_launch(void* const* d_in, const int* in_sizes, int n_in,
                              void* d_out, int out_size, void* d_ws, size_t ws_size,
                              hipStream_t stream)
{
    const int*   x_t  = (const int*)  d_in[0];
    const float* emb  = (const float*)d_in[1];
    const float* temp = (const float*)d_in[2];
    const float* Wq   = (const float*)d_in[3];
    const float* Wk   = (const float*)d_in[4];
    const float* Wv   = (const float*)d_in[5];
    const float* Wo   = (const float*)d_in[6];
    const float* bq   = (const float*)d_in[7];
    const float* bk   = (const float*)d_in[8];
    const float* bv   = (const float*)d_in[9];
    const float* bo   = (const float*)d_in[10];
    const float* W1   = (const float*)d_in[11];
    const float* b1   = (const float*)d_in[12];
    const float* W2   = (const float*)d_in[13];
    const float* b2   = (const float*)d_in[14];
    const float* ln1s = (const float*)d_in[15];
    const float* ln1b = (const float*)d_in[16];
    const float* ln2s = (const float*)d_in[17];
    const float* ln2b = (const float*)d_in[18];

    float* out = (float*)d_out;
    char*  wsb = (char*)d_ws;

    float*    X    = (float*)   (wsb + 0);
    ushort_t* Qb   = (ushort_t*)(wsb + 524288);
    ushort_t* Kb   = (ushort_t*)(wsb + 786432);
    ushort_t* Vb   = (ushort_t*)(wsb + 1048576);
    ushort_t* Ob   = (ushort_t*)(wsb + 1310720);
    ushort_t* Xb   = (ushort_t*)(wsb + 1572864);
    ushort_t* Ffb  = (ushort_t*)(wsb + 1835008);
    ushort_t* embB = (ushort_t*)(wsb + 3932160);
    ushort_t* WT   = (ushort_t*)(wsb + 4194304);
    ushort_t* W1T  = (ushort_t*)(wsb + 5242880);
    ushort_t* W2T  = (ushort_t*)(wsb + 7340032);

    prep_k<<<3072, 256, 0, stream>>>(x_t, emb, X, Xb, embB,
                                     Wq, Wk, Wv, Wo, W1, W2, WT, W1T, W2T);

    for (int l = 0; l < L_; ++l) {
        const ushort_t* WTl  = WT  + (size_t)l * (4 * D_ * D_);
        const ushort_t* W1Tl = W1T + (size_t)l * (D_ * FF_);
        const ushort_t* W2Tl = W2T + (size_t)l * (FF_ * D_);

        qkv_k<<<dim3(4, 8, 3), 256, 0, stream>>>(
            Xb, WTl, bq + l * D_, bk + l * D_, bv + l * D_, Qb, Kb, Vb);

        attn_k<<<dim3(32, 4), 256, 0, stream>>>(Qb, Kb, Vb, Ob);

        woln_k<<<16, 256, 0, stream>>>(Ob, WTl + 3 * D_ * D_, bo + l * D_,
                                       X, Xb, ln1s + l * D_, ln1b + l * D_);

        mgemm_k<1, 1, 1><<<dim3(32, 8, 1), 256, 0, stream>>>(
            Xb, W1Tl, b1 + l * FF_, nullptr, Ffb, T_, FF_, D_, D_);

        w2ln_k<<<16, 512, 0, stream>>>(Ffb, W2Tl, b2 + l * D_,
                                       X, Xb, ln2s + l * D_, ln2b + l * D_);
    }

    bcast_k<<<512, 256, 0, stream>>>(Xb, embB, temp, out);
}

// Round 4
// 187.872 us; speedup vs baseline: 1.3316x; 1.3316x over previous
//
#include <hip/hip_runtime.h>
#include <math.h>

// Problem constants (SemanticAwareTransitions_9826885173968)
#define V_  512
#define D_  256
#define H_  8
#define DH_ 32
#define FF_ 2048
#define L_  2
#define B_  4
#define S_  128
#define T_  (B_*S_)   // 512 tokens

typedef float f32x4 __attribute__((ext_vector_type(4)));
typedef short s16x8 __attribute__((ext_vector_type(8)));
typedef unsigned short u16x4 __attribute__((ext_vector_type(4)));
typedef unsigned short ushort_t;

// fp32 -> bf16 bits, round-to-nearest-even
__device__ __forceinline__ ushort_t f2b(float f) {
    unsigned int u = __builtin_bit_cast(unsigned int, f);
    u += 0x7FFFu + ((u >> 16) & 1u);
    return (ushort_t)(u >> 16);
}
__device__ __forceinline__ float b2f(ushort_t h) {
    unsigned int u = ((unsigned int)h) << 16;
    return __builtin_bit_cast(float, u);
}

__device__ __forceinline__ float waveReduceSum(float v) {
#pragma unroll
    for (int off = 32; off > 0; off >>= 1) v += __shfl_xor(v, off);
    return v;
}
__device__ __forceinline__ float waveReduceMax(float v) {
#pragma unroll
    for (int off = 32; off > 0; off >>= 1) v = fmaxf(v, __shfl_xor(v, off));
    return v;
}

// ---------------------------------------------------------------------------
// bf16 MFMA GEMM (64x64 tile, BK=32, 4 waves).
// mfma_f32_16x16x32_bf16 D-layout: col=lane&15, row=(lane>>4)*4+reg.
// ---------------------------------------------------------------------------
template<int RELU, int OUTB, int BIAS>
__device__ __forceinline__ void mgemm_body(
    const ushort_t* __restrict__ A, const ushort_t* __restrict__ BT,
    const float* __restrict__ bias, float* __restrict__ Cf,
    ushort_t* __restrict__ Cb, int M, int N, int K, int kBegin, int kSteps)
{
    __shared__ ushort_t Al[64][40];
    __shared__ ushort_t Bl[64][40];
    const int tid  = threadIdx.x;
    const int m0   = blockIdx.y * 64, n0 = blockIdx.x * 64;
    const int lane = tid & 63, w = tid >> 6;
    const int srow = tid >> 2, sseg = (tid & 3) * 8;
    const int l15  = lane & 15,  kg = (lane >> 4) * 8;

    f32x4 acc0 = {0.f,0.f,0.f,0.f}, acc1 = acc0, acc2 = acc0, acc3 = acc0;

    for (int kt = 0; kt < kSteps; ++kt) {
        const int k0 = kBegin + kt * 32;
        s16x8 av = *(const s16x8*)&A [(size_t)(m0 + srow) * K + k0 + sseg];
        s16x8 bv = *(const s16x8*)&BT[(size_t)(n0 + srow) * K + k0 + sseg];
        __syncthreads();
        *(s16x8*)&Al[srow][sseg] = av;
        *(s16x8*)&Bl[srow][sseg] = bv;
        __syncthreads();
        s16x8 bfr = *(const s16x8*)&Bl[w * 16 + l15][kg];
        s16x8 a0  = *(const s16x8*)&Al[     l15][kg];
        s16x8 a1  = *(const s16x8*)&Al[16 + l15][kg];
        s16x8 a2  = *(const s16x8*)&Al[32 + l15][kg];
        s16x8 a3  = *(const s16x8*)&Al[48 + l15][kg];
        acc0 = __builtin_amdgcn_mfma_f32_16x16x32_bf16(a0, bfr, acc0, 0, 0, 0);
        acc1 = __builtin_amdgcn_mfma_f32_16x16x32_bf16(a1, bfr, acc1, 0, 0, 0);
        acc2 = __builtin_amdgcn_mfma_f32_16x16x32_bf16(a2, bfr, acc2, 0, 0, 0);
        acc3 = __builtin_amdgcn_mfma_f32_16x16x32_bf16(a3, bfr, acc3, 0, 0, 0);
    }

    const int col = n0 + w * 16 + l15;
    const float bb = BIAS ? bias[col] : 0.f;
    f32x4 accs[4] = {acc0, acc1, acc2, acc3};
#pragma unroll
    for (int r = 0; r < 4; ++r) {
#pragma unroll
        for (int e = 0; e < 4; ++e) {
            const int row = m0 + r * 16 + (lane >> 4) * 4 + e;
            float v = accs[r][e] + bb;
            if (RELU) v = fmaxf(v, 0.f);
            if (OUTB) Cb[(size_t)row * N + col] = f2b(v);
            else      Cf[(size_t)row * N + col] = v;
        }
    }
}

// Split-K: z<2 writes Cf0 + z*M*N ; z>=2 writes Cf1 + (z-2)*M*N (fp32).
template<int RELU, int OUTB, int BIAS>
__global__ __launch_bounds__(256) void mgemm_k(const ushort_t* A, const ushort_t* BT,
    const float* bias, float* Cf0, float* Cf1, ushort_t* Cb,
    int M, int N, int K, int kChunk)
{
    const int z = blockIdx.z;
    float* Cfz = nullptr;
    if (Cf0) Cfz = (z < 2) ? Cf0 + (size_t)z * M * N
                           : Cf1 + (size_t)(z - 2) * M * N;
    mgemm_body<RELU, OUTB, BIAS>(A, BT, bias, Cfz, Cb, M, N, K,
                                 z * kChunk, kChunk / 32);
}

__global__ __launch_bounds__(256) void qkv_k(const ushort_t* Xb, const ushort_t* WT,
    const float* bq, const float* bk, const float* bv,
    ushort_t* Qb, ushort_t* Kb, ushort_t* Vb)
{
    const int z = blockIdx.z;
    const ushort_t* bt = WT + (size_t)z * (D_ * D_);
    const float* bias; ushort_t* out;
    if (z == 0)      { bias = bq; out = Qb; }
    else if (z == 1) { bias = bk; out = Kb; }
    else             { bias = bv; out = Vb; }
    mgemm_body<0, 1, 1>(Xb, bt, bias, nullptr, out, T_, D_, D_, 0, D_ / 32);
}

// ---------------------------------------------------------------------------
// prep: blocks [0,512) = embedding gather (+bf16 X and emb); [512,3072) =
// weight transpose fp32 [R][C] -> bf16 [C][R] in 32x32 LDS tiles.
// ---------------------------------------------------------------------------
__global__ __launch_bounds__(256) void prep_k(const int* __restrict__ xt,
    const float* __restrict__ emb, float* __restrict__ X,
    ushort_t* __restrict__ Xb, ushort_t* __restrict__ embB,
    const float* __restrict__ Wq, const float* __restrict__ Wk,
    const float* __restrict__ Wv, const float* __restrict__ Wo,
    const float* __restrict__ W1, const float* __restrict__ W2,
    ushort_t* __restrict__ WT, ushort_t* __restrict__ W1T, ushort_t* __restrict__ W2T)
{
    __shared__ float Tl[32][33];
    const int tid = threadIdx.x;
    if (blockIdx.x < 512) {
        const int idx = blockIdx.x * 256 + tid;       // < T_*D_ == V_*D_
        const int t = idx >> 8, d = idx & 255;
        const float v = emb[(size_t)xt[t] * D_ + d];
        X[idx]  = v;
        Xb[idx] = f2b(v);
        embB[idx] = f2b(emb[idx]);
        return;
    }
    const int id = blockIdx.x - 512;
    const int l  = id >= 1280 ? 1 : 0;
    const int t  = id - l * 1280;
    const float* src; ushort_t* dst; int R, C, rt, ct;
    if (t < 256) {
        const int kind = t >> 6, tl = t & 63;
        const float* s0 = (kind == 0) ? Wq : (kind == 1) ? Wk : (kind == 2) ? Wv : Wo;
        src = s0 + (size_t)l * (D_ * D_);
        dst = WT + (size_t)l * (4 * D_ * D_) + (size_t)kind * (D_ * D_);
        R = D_; C = D_; rt = tl >> 3; ct = tl & 7;
    } else if (t < 768) {
        const int tl = t - 256;
        src = W1 + (size_t)l * (D_ * FF_); dst = W1T + (size_t)l * (D_ * FF_);
        R = D_; C = FF_; rt = tl >> 6; ct = tl & 63;
    } else {
        const int tl = t - 768;
        src = W2 + (size_t)l * (FF_ * D_); dst = W2T + (size_t)l * (FF_ * D_);
        R = FF_; C = D_; rt = tl >> 3; ct = tl & 7;
    }
    const int r = tid >> 3, c4 = (tid & 7) * 4;
    f32x4 v = *(const f32x4*)&src[(size_t)(rt * 32 + r) * C + ct * 32 + c4];
    Tl[r][c4] = v[0]; Tl[r][c4 + 1] = v[1]; Tl[r][c4 + 2] = v[2]; Tl[r][c4 + 3] = v[3];
    __syncthreads();
    u16x4 ov;
    ov[0] = f2b(Tl[c4 + 0][r]); ov[1] = f2b(Tl[c4 + 1][r]);
    ov[2] = f2b(Tl[c4 + 2][r]); ov[3] = f2b(Tl[c4 + 3][r]);
    *(u16x4*)&dst[(size_t)(ct * 32 + r) * R + rt * 32 + c4] = ov;
}

// ---------------------------------------------------------------------------
// x = LN(x + sum parts + bias) * s + b ; writes fp32 X and bf16 Xb.
// nparts == 1 (p0 only) or 4 (p0 has 2, p1 has 2).
// ---------------------------------------------------------------------------
__global__ __launch_bounds__(256) void add_ln_k(
    const float* __restrict__ p0, const float* __restrict__ p1, int nparts,
    const float* __restrict__ bias, float* __restrict__ X,
    ushort_t* __restrict__ Xb, const float* __restrict__ s,
    const float* __restrict__ b)
{
    __shared__ float red[4];
    const int row = blockIdx.x, tid = threadIdx.x;
    const size_t off = (size_t)row * D_ + tid;
    const size_t TD = (size_t)T_ * D_;
    float a = X[off] + bias[tid] + p0[off];
    if (nparts == 4) a += p0[TD + off] + p1[off] + p1[TD + off];

    float ws_ = waveReduceSum(a);
    if ((tid & 63) == 0) red[tid >> 6] = ws_;
    __syncthreads();
    const float mean = (red[0] + red[1] + red[2] + red[3]) * (1.f / D_);
    __syncthreads();
    const float d = a - mean;
    float vs = waveReduceSum(d * d);
    if ((tid & 63) == 0) red[tid >> 6] = vs;
    __syncthreads();
    const float var = (red[0] + red[1] + red[2] + red[3]) * (1.f / D_);
    const float y = d * rsqrtf(var + 1e-5f) * s[tid] + b[tid];
    X[off]  = y;
    Xb[off] = f2b(y);
}

// ---------------------------------------------------------------------------
// Fused attention: one block per (b,h,q-quarter). fp32 math, bf16 I/O.
// ---------------------------------------------------------------------------
__global__ __launch_bounds__(256) void attn_k(const ushort_t* __restrict__ Qb,
    const ushort_t* __restrict__ Kb, const ushort_t* __restrict__ Vb,
    ushort_t* __restrict__ Ob)
{
    __shared__ float Qs[32][36], Ks[128][36], Vs[128][36], Ps[32][132];
    const int bh = blockIdx.x, b = bh >> 3, h = bh & 7;
    const int i0 = blockIdx.y * 32;
    const int tid = threadIdx.x;

#pragma unroll
    for (int it = 0; it < 2; ++it) {                 // K,V: 512 8-elem chunks
        const int g = it * 256 + tid;
        const int r = g >> 2, c8 = (g & 3) * 8;
        s16x8 kv = *(const s16x8*)&Kb[(size_t)(b * S_ + r) * D_ + h * DH_ + c8];
        s16x8 vv = *(const s16x8*)&Vb[(size_t)(b * S_ + r) * D_ + h * DH_ + c8];
        f32x4 klo = {b2f((ushort_t)kv[0]), b2f((ushort_t)kv[1]), b2f((ushort_t)kv[2]), b2f((ushort_t)kv[3])};
        f32x4 khi = {b2f((ushort_t)kv[4]), b2f((ushort_t)kv[5]), b2f((ushort_t)kv[6]), b2f((ushort_t)kv[7])};
        f32x4 vlo = {b2f((ushort_t)vv[0]), b2f((ushort_t)vv[1]), b2f((ushort_t)vv[2]), b2f((ushort_t)vv[3])};
        f32x4 vhi = {b2f((ushort_t)vv[4]), b2f((ushort_t)vv[5]), b2f((ushort_t)vv[6]), b2f((ushort_t)vv[7])};
        *(f32x4*)&Ks[r][c8]     = klo;  *(f32x4*)&Ks[r][c8 + 4] = khi;
        *(f32x4*)&Vs[r][c8]     = vlo;  *(f32x4*)&Vs[r][c8 + 4] = vhi;
    }
    if (tid < 128) {                                  // Q: 128 chunks
        const int r = tid >> 2, c8 = (tid & 3) * 8;
        s16x8 qv = *(const s16x8*)&Qb[(size_t)(b * S_ + i0 + r) * D_ + h * DH_ + c8];
        f32x4 qlo = {b2f((ushort_t)qv[0]), b2f((ushort_t)qv[1]), b2f((ushort_t)qv[2]), b2f((ushort_t)qv[3])};
        f32x4 qhi = {b2f((ushort_t)qv[4]), b2f((ushort_t)qv[5]), b2f((ushort_t)qv[6]), b2f((ushort_t)qv[7])};
        *(f32x4*)&Qs[r][c8] = qlo;  *(f32x4*)&Qs[r][c8 + 4] = qhi;
    }
    __syncthreads();

    const int i = tid >> 3, jg = tid & 7;
    const float sc = 0.17677669529663687f;   // 1/sqrt(32)
    float sv[16];
    float mx = -1e30f;
#pragma unroll
    for (int jj = 0; jj < 16; ++jj) {
        const int j = jg + jj * 8;
        f32x4 a4 = {0.f,0.f,0.f,0.f};
#pragma unroll
        for (int kk = 0; kk < 8; ++kk) {
            f32x4 q = *(const f32x4*)&Qs[i][kk * 4];
            f32x4 k = *(const f32x4*)&Ks[j][kk * 4];
            a4 += q * k;
        }
        const float sdot = (a4[0] + a4[1] + a4[2] + a4[3]) * sc;
        sv[jj] = sdot;
        mx = fmaxf(mx, sdot);
    }
    mx = fmaxf(mx, __shfl_xor(mx, 1));
    mx = fmaxf(mx, __shfl_xor(mx, 2));
    mx = fmaxf(mx, __shfl_xor(mx, 4));
    float sum = 0.f;
#pragma unroll
    for (int jj = 0; jj < 16; ++jj) {
        const float e = __expf(sv[jj] - mx);
        Ps[i][jg + jj * 8] = e;
        sum += e;
    }
    sum += __shfl_xor(sum, 1);
    sum += __shfl_xor(sum, 2);
    sum += __shfl_xor(sum, 4);
    const float inv = 1.f / sum;
    __syncthreads();

    const int dg = tid & 7;
    f32x4 o = {0.f,0.f,0.f,0.f};
#pragma unroll 4
    for (int j = 0; j < 128; ++j) {
        const float p = Ps[i][j];
        f32x4 vv = *(const f32x4*)&Vs[j][dg * 4];
        o += vv * p;
    }
    u16x4 ov;
    ov[0] = f2b(o[0] * inv); ov[1] = f2b(o[1] * inv);
    ov[2] = f2b(o[2] * inv); ov[3] = f2b(o[3] * inv);
    *(u16x4*)&Ob[(size_t)(b * S_ + i0 + i) * D_ + h * DH_ + dg * 4] = ov;
}

// ---------------------------------------------------------------------------
// Fused final softmax + broadcast: block = (token t, quarter of row-range).
// Each block re-computes softmax(t) (cheap, 4x redundant) then streams 128
// rows of 2KB with nontemporal float4 stores.
// ---------------------------------------------------------------------------
__global__ __launch_bounds__(256) void bcast_k(const float* __restrict__ Lg,
    const float* __restrict__ temp, float* __restrict__ out)
{
    __shared__ float row[V_];
    __shared__ float red[4];
    const int blk = blockIdx.x, t = blk >> 2, quarter = blk & 3;
    const int tid = threadIdx.x;
    const float rT = 1.f / temp[0];
    const float l0 = Lg[(size_t)t * V_ + tid] * rT;
    const float l1 = Lg[(size_t)t * V_ + 256 + tid] * rT;
    float m = waveReduceMax(fmaxf(l0, l1));
    if ((tid & 63) == 0) red[tid >> 6] = m;
    __syncthreads();
    m = fmaxf(fmaxf(red[0], red[1]), fmaxf(red[2], red[3]));
    __syncthreads();
    const float e0 = __expf(l0 - m), e1 = __expf(l1 - m);
    float sblk = waveReduceSum(e0 + e1);
    if ((tid & 63) == 0) red[tid >> 6] = sblk;
    __syncthreads();
    const float inv = 1.f / (red[0] + red[1] + red[2] + red[3]);
    row[tid] = e0 * inv;
    row[tid + 256] = e1 * inv;
    __syncthreads();

    const int c = tid & 127, ihalf = tid >> 7;
    f32x4 v = *(const f32x4*)&row[c * 4];
    f32x4* dst = (f32x4*)out + (size_t)t * V_ * (V_ / 4);
#pragma unroll 4
    for (int r = 0; r < 64; ++r) {
        const int i = quarter * 128 + ihalf + r * 2;
        __builtin_nontemporal_store(v, &dst[(size_t)i * (V_ / 4) + c]);
    }
}

// ---------------------------------------------------------------------------
// Host launch. ws layout (bytes), total 10.0 MB:
//   0        X     fp32 512KB
//   524288   PartA fp32 2x512KB (split-K parts 0-1; alias Lg 1MB at end)
//   1572864  Qb    bf16 256KB  \
//   1835008  Kb    bf16 256KB   } parts 2-3 alias this 1MB during W2 GEMM
//   2097152  Vb    bf16 256KB   } (Qb..Ob dead at that point in the layer)
//   2359296  Ob    bf16 256KB  /
//   2621440  Xb    bf16 256KB
//   2883584  Ffb   bf16 2MB
//   4980736  embB  bf16 256KB
//   5242880  WT    bf16 1MB
//   6291456  W1T   bf16 2MB
//   8388608  W2T   bf16 2MB   -> end 10485760
// ---------------------------------------------------------------------------
extern "C" void kernel_launch(void* const* d_in, const int* in_sizes, int n_in,
                              void* d_out, int out_size, void* d_ws, size_t ws_size,
                              hipStream_t stream)
{
    const int*   x_t  = (const int*)  d_in[0];
    const float* emb  = (const float*)d_in[1];
    const float* temp = (const float*)d_in[2];
    const float* Wq   = (const float*)d_in[3];
    const float* Wk   = (const float*)d_in[4];
    const float* Wv   = (const float*)d_in[5];
    const float* Wo   = (const float*)d_in[6];
    const float* bq   = (const float*)d_in[7];
    const float* bk   = (const float*)d_in[8];
    const float* bv   = (const float*)d_in[9];
    const float* bo   = (const float*)d_in[10];
    const float* W1   = (const float*)d_in[11];
    const float* b1   = (const float*)d_in[12];
    const float* W2   = (const float*)d_in[13];
    const float* b2   = (const float*)d_in[14];
    const float* ln1s = (const float*)d_in[15];
    const float* ln1b = (const float*)d_in[16];
    const float* ln2s = (const float*)d_in[17];
    const float* ln2b = (const float*)d_in[18];

    float* out = (float*)d_out;
    char*  wsb = (char*)d_ws;

    float*    X     = (float*)   (wsb + 0);
    float*    PartA = (float*)   (wsb + 524288);
    float*    Lg    = PartA;                        // alias (disjoint lifetime)
    ushort_t* Qb    = (ushort_t*)(wsb + 1572864);
    float*    PartB = (float*)   (wsb + 1572864);   // alias Qb..Ob (parts 2-3)
    ushort_t* Kb    = (ushort_t*)(wsb + 1835008);
    ushort_t* Vb    = (ushort_t*)(wsb + 2097152);
    ushort_t* Ob    = (ushort_t*)(wsb + 2359296);
    ushort_t* Xb    = (ushort_t*)(wsb + 2621440);
    ushort_t* Ffb   = (ushort_t*)(wsb + 2883584);
    ushort_t* embB  = (ushort_t*)(wsb + 4980736);
    ushort_t* WT    = (ushort_t*)(wsb + 5242880);
    ushort_t* W1T   = (ushort_t*)(wsb + 6291456);
    ushort_t* W2T   = (ushort_t*)(wsb + 8388608);

    prep_k<<<3072, 256, 0, stream>>>(x_t, emb, X, Xb, embB,
                                     Wq, Wk, Wv, Wo, W1, W2, WT, W1T, W2T);

    for (int l = 0; l < L_; ++l) {
        const ushort_t* WTl  = WT  + (size_t)l * (4 * D_ * D_);
        const ushort_t* W1Tl = W1T + (size_t)l * (D_ * FF_);
        const ushort_t* W2Tl = W2T + (size_t)l * (FF_ * D_);

        qkv_k<<<dim3(4, 8, 3), 256, 0, stream>>>(
            Xb, WTl, bq + l * D_, bk + l * D_, bv + l * D_, Qb, Kb, Vb);

        attn_k<<<dim3(32, 4), 256, 0, stream>>>(Qb, Kb, Vb, Ob);

        // o @ Wo -> PartA[0] (fp32); bias bo folded into add_ln
        mgemm_k<0, 0, 0><<<dim3(4, 8, 1), 256, 0, stream>>>(
            Ob, WTl + 3 * D_ * D_, nullptr, PartA, nullptr, nullptr,
            T_, D_, D_, D_);
        add_ln_k<<<T_, 256, 0, stream>>>(PartA, nullptr, 1, bo + l * D_,
                                         X, Xb, ln1s + l * D_, ln1b + l * D_);

        // relu(x @ W1 + b1) -> Ffb (bf16)
        mgemm_k<1, 1, 1><<<dim3(32, 8, 1), 256, 0, stream>>>(
            Xb, W1Tl, b1 + l * FF_, nullptr, nullptr, Ffb, T_, FF_, D_, D_);

        // Ffb @ W2 split-K z=4 -> PartA[0..1] + PartB[0..1]; b2 in add_ln
        mgemm_k<0, 0, 0><<<dim3(4, 8, 4), 256, 0, stream>>>(
            Ffb, W2Tl, nullptr, PartA, PartB, nullptr, T_, D_, FF_, FF_ / 4);
        add_ln_k<<<T_, 256, 0, stream>>>(PartA, PartB, 4, b2 + l * D_,
                                         X, Xb, ln2s + l * D_, ln2b + l * D_);
    }

    // logits = Xb @ embB^T -> Lg (fp32)
    mgemm_k<0, 0, 0><<<dim3(8, 8, 1), 256, 0, stream>>>(
        Xb, embB, nullptr, Lg, nullptr, nullptr, T_, V_, D_, D_);

    bcast_k<<<T_ * 4, 256, 0, stream>>>(Lg, temp, out);
}

// Round 5
// 179.986 us; speedup vs baseline: 1.3900x; 1.0438x over previous
//
#include <hip/hip_runtime.h>
#include <math.h>

// Problem constants (SemanticAwareTransitions_9826885173968)
#define V_  512
#define D_  256
#define H_  8
#define DH_ 32
#define FF_ 2048
#define L_  2
#define B_  4
#define S_  128
#define T_  (B_*S_)   // 512 tokens

typedef float f32x4 __attribute__((ext_vector_type(4)));
typedef short s16x8 __attribute__((ext_vector_type(8)));
typedef unsigned short u16x4 __attribute__((ext_vector_type(4)));
typedef unsigned short ushort_t;

// fp32 -> bf16 bits, round-to-nearest-even
__device__ __forceinline__ ushort_t f2b(float f) {
    unsigned int u = __builtin_bit_cast(unsigned int, f);
    u += 0x7FFFu + ((u >> 16) & 1u);
    return (ushort_t)(u >> 16);
}
__device__ __forceinline__ float b2f(ushort_t h) {
    unsigned int u = ((unsigned int)h) << 16;
    return __builtin_bit_cast(float, u);
}

__device__ __forceinline__ float waveReduceSum(float v) {
#pragma unroll
    for (int off = 32; off > 0; off >>= 1) v += __shfl_xor(v, off);
    return v;
}
__device__ __forceinline__ float waveReduceMax(float v) {
#pragma unroll
    for (int off = 32; off > 0; off >>= 1) v = fmaxf(v, __shfl_xor(v, off));
    return v;
}

// ---------------------------------------------------------------------------
// bf16 MFMA GEMM (64x64 tile, BK=32, 4 waves), double-buffered 1-barrier
// pipeline: global loads for step t+1 stay IN FLIGHT across the barrier
// (asm lgkmcnt-only barrier -- __syncthreads would drain vmcnt(0) and
// serialize the full load latency every step). ds_write of the next buffer
// auto-waits vmcnt after the MFMAs have covered the latency.
// mfma_f32_16x16x32_bf16 D-layout: col=lane&15, row=(lane>>4)*4+reg.
// ---------------------------------------------------------------------------
template<int RELU, int OUTB, int BIAS>
__device__ __forceinline__ void mgemm_body(
    const ushort_t* __restrict__ A, const ushort_t* __restrict__ BT,
    const float* __restrict__ bias, float* __restrict__ Cf,
    ushort_t* __restrict__ Cb, int M, int N, int K, int kBegin, int kSteps)
{
    __shared__ ushort_t Al[2][64][40];
    __shared__ ushort_t Bl[2][64][40];
    const int tid  = threadIdx.x;
    const int m0   = blockIdx.y * 64, n0 = blockIdx.x * 64;
    const int lane = tid & 63, w = tid >> 6;
    const int srow = tid >> 2, sseg = (tid & 3) * 8;
    const int l15  = lane & 15,  kg = (lane >> 4) * 8;

    f32x4 acc0 = {0.f,0.f,0.f,0.f}, acc1 = acc0, acc2 = acc0, acc3 = acc0;

    const ushort_t* Aptr = &A [(size_t)(m0 + srow) * K + kBegin + sseg];
    const ushort_t* Bptr = &BT[(size_t)(n0 + srow) * K + kBegin + sseg];

    // prologue: stage tile 0 into buffer 0
    s16x8 av = *(const s16x8*)Aptr;
    s16x8 bv = *(const s16x8*)Bptr;
    *(s16x8*)&Al[0][srow][sseg] = av;
    *(s16x8*)&Bl[0][srow][sseg] = bv;

    for (int kt = 0; kt < kSteps; ++kt) {
        const int cur = kt & 1;
        const bool more = (kt + 1 < kSteps);
        if (more) {                      // issue next tile's loads (in flight)
            av = *(const s16x8*)(Aptr + (size_t)(kt + 1) * 32);
            bv = *(const s16x8*)(Bptr + (size_t)(kt + 1) * 32);
        }
        // own LDS ops drained (writes from prev step visible after barrier);
        // global loads NOT drained -- they complete under the MFMAs below.
        asm volatile("s_waitcnt lgkmcnt(0)\n\ts_barrier" ::: "memory");

        s16x8 bfr = *(const s16x8*)&Bl[cur][w * 16 + l15][kg];
        s16x8 a0  = *(const s16x8*)&Al[cur][     l15][kg];
        s16x8 a1  = *(const s16x8*)&Al[cur][16 + l15][kg];
        s16x8 a2  = *(const s16x8*)&Al[cur][32 + l15][kg];
        s16x8 a3  = *(const s16x8*)&Al[cur][48 + l15][kg];
        acc0 = __builtin_amdgcn_mfma_f32_16x16x32_bf16(a0, bfr, acc0, 0, 0, 0);
        acc1 = __builtin_amdgcn_mfma_f32_16x16x32_bf16(a1, bfr, acc1, 0, 0, 0);
        acc2 = __builtin_amdgcn_mfma_f32_16x16x32_bf16(a2, bfr, acc2, 0, 0, 0);
        acc3 = __builtin_amdgcn_mfma_f32_16x16x32_bf16(a3, bfr, acc3, 0, 0, 0);

        if (more) {                      // auto vmcnt-wait on av/bv here
            *(s16x8*)&Al[cur ^ 1][srow][sseg] = av;
            *(s16x8*)&Bl[cur ^ 1][srow][sseg] = bv;
        }
    }

    const int col = n0 + w * 16 + l15;
    const float bb = BIAS ? bias[col] : 0.f;
    f32x4 accs[4] = {acc0, acc1, acc2, acc3};
#pragma unroll
    for (int r = 0; r < 4; ++r) {
#pragma unroll
        for (int e = 0; e < 4; ++e) {
            const int row = m0 + r * 16 + (lane >> 4) * 4 + e;
            float v = accs[r][e] + bb;
            if (RELU) v = fmaxf(v, 0.f);
            if (OUTB) Cb[(size_t)row * N + col] = f2b(v);
            else      Cf[(size_t)row * N + col] = v;
        }
    }
}

// Split-K: z<2 writes Cf0 + z*M*N ; z>=2 writes Cf1 + (z-2)*M*N (fp32).
template<int RELU, int OUTB, int BIAS>
__global__ __launch_bounds__(256) void mgemm_k(const ushort_t* A, const ushort_t* BT,
    const float* bias, float* Cf0, float* Cf1, ushort_t* Cb,
    int M, int N, int K, int kChunk)
{
    const int z = blockIdx.z;
    float* Cfz = nullptr;
    if (Cf0) Cfz = (z < 2) ? Cf0 + (size_t)z * M * N
                           : Cf1 + (size_t)(z - 2) * M * N;
    mgemm_body<RELU, OUTB, BIAS>(A, BT, bias, Cfz, Cb, M, N, K,
                                 z * kChunk, kChunk / 32);
}

__global__ __launch_bounds__(256) void qkv_k(const ushort_t* Xb, const ushort_t* WT,
    const float* bq, const float* bk, const float* bv,
    ushort_t* Qb, ushort_t* Kb, ushort_t* Vb)
{
    const int z = blockIdx.z;
    const ushort_t* bt = WT + (size_t)z * (D_ * D_);
    const float* bias; ushort_t* out;
    if (z == 0)      { bias = bq; out = Qb; }
    else if (z == 1) { bias = bk; out = Kb; }
    else             { bias = bv; out = Vb; }
    mgemm_body<0, 1, 1>(Xb, bt, bias, nullptr, out, T_, D_, D_, 0, D_ / 32);
}

// ---------------------------------------------------------------------------
// prep: blocks [0,512) = embedding gather (+bf16 X and emb); [512,3072) =
// weight transpose fp32 [R][C] -> bf16 [C][R] in 32x32 LDS tiles.
// ---------------------------------------------------------------------------
__global__ __launch_bounds__(256) void prep_k(const int* __restrict__ xt,
    const float* __restrict__ emb, float* __restrict__ X,
    ushort_t* __restrict__ Xb, ushort_t* __restrict__ embB,
    const float* __restrict__ Wq, const float* __restrict__ Wk,
    const float* __restrict__ Wv, const float* __restrict__ Wo,
    const float* __restrict__ W1, const float* __restrict__ W2,
    ushort_t* __restrict__ WT, ushort_t* __restrict__ W1T, ushort_t* __restrict__ W2T)
{
    __shared__ float Tl[32][33];
    const int tid = threadIdx.x;
    if (blockIdx.x < 512) {
        const int idx = blockIdx.x * 256 + tid;       // < T_*D_ == V_*D_
        const int t = idx >> 8, d = idx & 255;
        const float v = emb[(size_t)xt[t] * D_ + d];
        X[idx]  = v;
        Xb[idx] = f2b(v);
        embB[idx] = f2b(emb[idx]);
        return;
    }
    const int id = blockIdx.x - 512;
    const int l  = id >= 1280 ? 1 : 0;
    const int t  = id - l * 1280;
    const float* src; ushort_t* dst; int R, C, rt, ct;
    if (t < 256) {
        const int kind = t >> 6, tl = t & 63;
        const float* s0 = (kind == 0) ? Wq : (kind == 1) ? Wk : (kind == 2) ? Wv : Wo;
        src = s0 + (size_t)l * (D_ * D_);
        dst = WT + (size_t)l * (4 * D_ * D_) + (size_t)kind * (D_ * D_);
        R = D_; C = D_; rt = tl >> 3; ct = tl & 7;
    } else if (t < 768) {
        const int tl = t - 256;
        src = W1 + (size_t)l * (D_ * FF_); dst = W1T + (size_t)l * (D_ * FF_);
        R = D_; C = FF_; rt = tl >> 6; ct = tl & 63;
    } else {
        const int tl = t - 768;
        src = W2 + (size_t)l * (FF_ * D_); dst = W2T + (size_t)l * (FF_ * D_);
        R = FF_; C = D_; rt = tl >> 3; ct = tl & 7;
    }
    const int r = tid >> 3, c4 = (tid & 7) * 4;
    f32x4 v = *(const f32x4*)&src[(size_t)(rt * 32 + r) * C + ct * 32 + c4];
    Tl[r][c4] = v[0]; Tl[r][c4 + 1] = v[1]; Tl[r][c4 + 2] = v[2]; Tl[r][c4 + 3] = v[3];
    __syncthreads();
    u16x4 ov;
    ov[0] = f2b(Tl[c4 + 0][r]); ov[1] = f2b(Tl[c4 + 1][r]);
    ov[2] = f2b(Tl[c4 + 2][r]); ov[3] = f2b(Tl[c4 + 3][r]);
    *(u16x4*)&dst[(size_t)(ct * 32 + r) * R + rt * 32 + c4] = ov;
}

// ---------------------------------------------------------------------------
// x = LN(x + sum parts + bias) * s + b ; writes fp32 X and bf16 Xb.
// nparts == 1 (p0 only) or 4 (p0 has 2, p1 has 2).
// ---------------------------------------------------------------------------
__global__ __launch_bounds__(256) void add_ln_k(
    const float* __restrict__ p0, const float* __restrict__ p1, int nparts,
    const float* __restrict__ bias, float* __restrict__ X,
    ushort_t* __restrict__ Xb, const float* __restrict__ s,
    const float* __restrict__ b)
{
    __shared__ float red[4];
    const int row = blockIdx.x, tid = threadIdx.x;
    const size_t off = (size_t)row * D_ + tid;
    const size_t TD = (size_t)T_ * D_;
    float a = X[off] + bias[tid] + p0[off];
    if (nparts == 4) a += p0[TD + off] + p1[off] + p1[TD + off];

    float ws_ = waveReduceSum(a);
    if ((tid & 63) == 0) red[tid >> 6] = ws_;
    __syncthreads();
    const float mean = (red[0] + red[1] + red[2] + red[3]) * (1.f / D_);
    __syncthreads();
    const float d = a - mean;
    float vs = waveReduceSum(d * d);
    if ((tid & 63) == 0) red[tid >> 6] = vs;
    __syncthreads();
    const float var = (red[0] + red[1] + red[2] + red[3]) * (1.f / D_);
    const float y = d * rsqrtf(var + 1e-5f) * s[tid] + b[tid];
    X[off]  = y;
    Xb[off] = f2b(y);
}

// ---------------------------------------------------------------------------
// Fused attention: one block per (b,h,q-quarter). fp32 math, bf16 I/O.
// ---------------------------------------------------------------------------
__global__ __launch_bounds__(256) void attn_k(const ushort_t* __restrict__ Qb,
    const ushort_t* __restrict__ Kb, const ushort_t* __restrict__ Vb,
    ushort_t* __restrict__ Ob)
{
    __shared__ float Qs[32][36], Ks[128][36], Vs[128][36], Ps[32][132];
    const int bh = blockIdx.x, b = bh >> 3, h = bh & 7;
    const int i0 = blockIdx.y * 32;
    const int tid = threadIdx.x;

#pragma unroll
    for (int it = 0; it < 2; ++it) {                 // K,V: 512 8-elem chunks
        const int g = it * 256 + tid;
        const int r = g >> 2, c8 = (g & 3) * 8;
        s16x8 kv = *(const s16x8*)&Kb[(size_t)(b * S_ + r) * D_ + h * DH_ + c8];
        s16x8 vv = *(const s16x8*)&Vb[(size_t)(b * S_ + r) * D_ + h * DH_ + c8];
        f32x4 klo = {b2f((ushort_t)kv[0]), b2f((ushort_t)kv[1]), b2f((ushort_t)kv[2]), b2f((ushort_t)kv[3])};
        f32x4 khi = {b2f((ushort_t)kv[4]), b2f((ushort_t)kv[5]), b2f((ushort_t)kv[6]), b2f((ushort_t)kv[7])};
        f32x4 vlo = {b2f((ushort_t)vv[0]), b2f((ushort_t)vv[1]), b2f((ushort_t)vv[2]), b2f((ushort_t)vv[3])};
        f32x4 vhi = {b2f((ushort_t)vv[4]), b2f((ushort_t)vv[5]), b2f((ushort_t)vv[6]), b2f((ushort_t)vv[7])};
        *(f32x4*)&Ks[r][c8]     = klo;  *(f32x4*)&Ks[r][c8 + 4] = khi;
        *(f32x4*)&Vs[r][c8]     = vlo;  *(f32x4*)&Vs[r][c8 + 4] = vhi;
    }
    if (tid < 128) {                                  // Q: 128 chunks
        const int r = tid >> 2, c8 = (tid & 3) * 8;
        s16x8 qv = *(const s16x8*)&Qb[(size_t)(b * S_ + i0 + r) * D_ + h * DH_ + c8];
        f32x4 qlo = {b2f((ushort_t)qv[0]), b2f((ushort_t)qv[1]), b2f((ushort_t)qv[2]), b2f((ushort_t)qv[3])};
        f32x4 qhi = {b2f((ushort_t)qv[4]), b2f((ushort_t)qv[5]), b2f((ushort_t)qv[6]), b2f((ushort_t)qv[7])};
        *(f32x4*)&Qs[r][c8] = qlo;  *(f32x4*)&Qs[r][c8 + 4] = qhi;
    }
    __syncthreads();

    const int i = tid >> 3, jg = tid & 7;
    const float sc = 0.17677669529663687f;   // 1/sqrt(32)
    float sv[16];
    float mx = -1e30f;
#pragma unroll
    for (int jj = 0; jj < 16; ++jj) {
        const int j = jg + jj * 8;
        f32x4 a4 = {0.f,0.f,0.f,0.f};
#pragma unroll
        for (int kk = 0; kk < 8; ++kk) {
            f32x4 q = *(const f32x4*)&Qs[i][kk * 4];
            f32x4 k = *(const f32x4*)&Ks[j][kk * 4];
            a4 += q * k;
        }
        const float sdot = (a4[0] + a4[1] + a4[2] + a4[3]) * sc;
        sv[jj] = sdot;
        mx = fmaxf(mx, sdot);
    }
    mx = fmaxf(mx, __shfl_xor(mx, 1));
    mx = fmaxf(mx, __shfl_xor(mx, 2));
    mx = fmaxf(mx, __shfl_xor(mx, 4));
    float sum = 0.f;
#pragma unroll
    for (int jj = 0; jj < 16; ++jj) {
        const float e = __expf(sv[jj] - mx);
        Ps[i][jg + jj * 8] = e;
        sum += e;
    }
    sum += __shfl_xor(sum, 1);
    sum += __shfl_xor(sum, 2);
    sum += __shfl_xor(sum, 4);
    const float inv = 1.f / sum;
    __syncthreads();

    const int dg = tid & 7;
    f32x4 o = {0.f,0.f,0.f,0.f};
#pragma unroll 4
    for (int j = 0; j < 128; ++j) {
        const float p = Ps[i][j];
        f32x4 vv = *(const f32x4*)&Vs[j][dg * 4];
        o += vv * p;
    }
    u16x4 ov;
    ov[0] = f2b(o[0] * inv); ov[1] = f2b(o[1] * inv);
    ov[2] = f2b(o[2] * inv); ov[3] = f2b(o[3] * inv);
    *(u16x4*)&Ob[(size_t)(b * S_ + i0 + i) * D_ + h * DH_ + dg * 4] = ov;
}

// ---------------------------------------------------------------------------
// Fused final softmax + broadcast: block = (token t, quarter of row-range).
// Each block re-computes softmax(t) (cheap, 4x redundant) then streams 128
// rows of 2KB with nontemporal float4 stores.
// ---------------------------------------------------------------------------
__global__ __launch_bounds__(256) void bcast_k(const float* __restrict__ Lg,
    const float* __restrict__ temp, float* __restrict__ out)
{
    __shared__ float row[V_];
    __shared__ float red[4];
    const int blk = blockIdx.x, t = blk >> 2, quarter = blk & 3;
    const int tid = threadIdx.x;
    const float rT = 1.f / temp[0];
    const float l0 = Lg[(size_t)t * V_ + tid] * rT;
    const float l1 = Lg[(size_t)t * V_ + 256 + tid] * rT;
    float m = waveReduceMax(fmaxf(l0, l1));
    if ((tid & 63) == 0) red[tid >> 6] = m;
    __syncthreads();
    m = fmaxf(fmaxf(red[0], red[1]), fmaxf(red[2], red[3]));
    __syncthreads();
    const float e0 = __expf(l0 - m), e1 = __expf(l1 - m);
    float sblk = waveReduceSum(e0 + e1);
    if ((tid & 63) == 0) red[tid >> 6] = sblk;
    __syncthreads();
    const float inv = 1.f / (red[0] + red[1] + red[2] + red[3]);
    row[tid] = e0 * inv;
    row[tid + 256] = e1 * inv;
    __syncthreads();

    const int c = tid & 127, ihalf = tid >> 7;
    f32x4 v = *(const f32x4*)&row[c * 4];
    f32x4* dst = (f32x4*)out + (size_t)t * V_ * (V_ / 4);
#pragma unroll 4
    for (int r = 0; r < 64; ++r) {
        const int i = quarter * 128 + ihalf + r * 2;
        __builtin_nontemporal_store(v, &dst[(size_t)i * (V_ / 4) + c]);
    }
}

// ---------------------------------------------------------------------------
// Host launch. ws layout (bytes), total 10.0 MB:
//   0        X     fp32 512KB
//   524288   PartA fp32 2x512KB (split-K parts 0-1; alias Lg 1MB at end)
//   1572864  Qb    bf16 256KB  \
//   1835008  Kb    bf16 256KB   } parts 2-3 alias this 1MB during W2 GEMM
//   2097152  Vb    bf16 256KB   } (Qb..Ob dead at that point in the layer)
//   2359296  Ob    bf16 256KB  /
//   2621440  Xb    bf16 256KB
//   2883584  Ffb   bf16 2MB
//   4980736  embB  bf16 256KB
//   5242880  WT    bf16 1MB
//   6291456  W1T   bf16 2MB
//   8388608  W2T   bf16 2MB   -> end 10485760
// ---------------------------------------------------------------------------
extern "C" void kernel_launch(void* const* d_in, const int* in_sizes, int n_in,
                              void* d_out, int out_size, void* d_ws, size_t ws_size,
                              hipStream_t stream)
{
    const int*   x_t  = (const int*)  d_in[0];
    const float* emb  = (const float*)d_in[1];
    const float* temp = (const float*)d_in[2];
    const float* Wq   = (const float*)d_in[3];
    const float* Wk   = (const float*)d_in[4];
    const float* Wv   = (const float*)d_in[5];
    const float* Wo   = (const float*)d_in[6];
    const float* bq   = (const float*)d_in[7];
    const float* bk   = (const float*)d_in[8];
    const float* bv   = (const float*)d_in[9];
    const float* bo   = (const float*)d_in[10];
    const float* W1   = (const float*)d_in[11];
    const float* b1   = (const float*)d_in[12];
    const float* W2   = (const float*)d_in[13];
    const float* b2   = (const float*)d_in[14];
    const float* ln1s = (const float*)d_in[15];
    const float* ln1b = (const float*)d_in[16];
    const float* ln2s = (const float*)d_in[17];
    const float* ln2b = (const float*)d_in[18];

    float* out = (float*)d_out;
    char*  wsb = (char*)d_ws;

    float*    X     = (float*)   (wsb + 0);
    float*    PartA = (float*)   (wsb + 524288);
    float*    Lg    = PartA;                        // alias (disjoint lifetime)
    ushort_t* Qb    = (ushort_t*)(wsb + 1572864);
    float*    PartB = (float*)   (wsb + 1572864);   // alias Qb..Ob (parts 2-3)
    ushort_t* Kb    = (ushort_t*)(wsb + 1835008);
    ushort_t* Vb    = (ushort_t*)(wsb + 2097152);
    ushort_t* Ob    = (ushort_t*)(wsb + 2359296);
    ushort_t* Xb    = (ushort_t*)(wsb + 2621440);
    ushort_t* Ffb   = (ushort_t*)(wsb + 2883584);
    ushort_t* embB  = (ushort_t*)(wsb + 4980736);
    ushort_t* WT    = (ushort_t*)(wsb + 5242880);
    ushort_t* W1T   = (ushort_t*)(wsb + 6291456);
    ushort_t* W2T   = (ushort_t*)(wsb + 8388608);

    prep_k<<<3072, 256, 0, stream>>>(x_t, emb, X, Xb, embB,
                                     Wq, Wk, Wv, Wo, W1, W2, WT, W1T, W2T);

    for (int l = 0; l < L_; ++l) {
        const ushort_t* WTl  = WT  + (size_t)l * (4 * D_ * D_);
        const ushort_t* W1Tl = W1T + (size_t)l * (D_ * FF_);
        const ushort_t* W2Tl = W2T + (size_t)l * (FF_ * D_);

        qkv_k<<<dim3(4, 8, 3), 256, 0, stream>>>(
            Xb, WTl, bq + l * D_, bk + l * D_, bv + l * D_, Qb, Kb, Vb);

        attn_k<<<dim3(32, 4), 256, 0, stream>>>(Qb, Kb, Vb, Ob);

        // o @ Wo -> PartA[0] (fp32); bias bo folded into add_ln
        mgemm_k<0, 0, 0><<<dim3(4, 8, 1), 256, 0, stream>>>(
            Ob, WTl + 3 * D_ * D_, nullptr, PartA, nullptr, nullptr,
            T_, D_, D_, D_);
        add_ln_k<<<T_, 256, 0, stream>>>(PartA, nullptr, 1, bo + l * D_,
                                         X, Xb, ln1s + l * D_, ln1b + l * D_);

        // relu(x @ W1 + b1) -> Ffb (bf16)
        mgemm_k<1, 1, 1><<<dim3(32, 8, 1), 256, 0, stream>>>(
            Xb, W1Tl, b1 + l * FF_, nullptr, nullptr, Ffb, T_, FF_, D_, D_);

        // Ffb @ W2 split-K z=4 -> PartA[0..1] + PartB[0..1]; b2 in add_ln
        mgemm_k<0, 0, 0><<<dim3(4, 8, 4), 256, 0, stream>>>(
            Ffb, W2Tl, nullptr, PartA, PartB, nullptr, T_, D_, FF_, FF_ / 4);
        add_ln_k<<<T_, 256, 0, stream>>>(PartA, PartB, 4, b2 + l * D_,
                                         X, Xb, ln2s + l * D_, ln2b + l * D_);
    }

    // logits = Xb @ embB^T -> Lg (fp32)
    mgemm_k<0, 0, 0><<<dim3(8, 8, 1), 256, 0, stream>>>(
        Xb, embB, nullptr, Lg, nullptr, nullptr, T_, V_, D_, D_);

    bcast_k<<<T_ * 4, 256, 0, stream>>>(Lg, temp, out);
}

// Round 6
// 172.181 us; speedup vs baseline: 1.4530x; 1.0453x over previous
//
#include <hip/hip_runtime.h>
#include <math.h>

// Problem constants (SemanticAwareTransitions_9826885173968)
#define V_  512
#define D_  256
#define H_  8
#define DH_ 32
#define FF_ 2048
#define L_  2
#define B_  4
#define S_  128
#define T_  (B_*S_)   // 512 tokens

typedef float f32x4 __attribute__((ext_vector_type(4)));
typedef short s16x8 __attribute__((ext_vector_type(8)));
typedef unsigned short u16x4 __attribute__((ext_vector_type(4)));
typedef unsigned short ushort_t;

// fp32 -> bf16 bits, round-to-nearest-even
__device__ __forceinline__ ushort_t f2b(float f) {
    unsigned int u = __builtin_bit_cast(unsigned int, f);
    u += 0x7FFFu + ((u >> 16) & 1u);
    return (ushort_t)(u >> 16);
}
__device__ __forceinline__ float b2f(ushort_t h) {
    unsigned int u = ((unsigned int)h) << 16;
    return __builtin_bit_cast(float, u);
}

__device__ __forceinline__ float waveReduceSum(float v) {
#pragma unroll
    for (int off = 32; off > 0; off >>= 1) v += __shfl_xor(v, off);
    return v;
}
__device__ __forceinline__ float waveReduceMax(float v) {
#pragma unroll
    for (int off = 32; off > 0; off >>= 1) v = fmaxf(v, __shfl_xor(v, off));
    return v;
}

// ---------------------------------------------------------------------------
// bf16 MFMA GEMM (64x64 tile, BK=64, 4 waves), double-buffered 1-barrier
// pipeline. BK=64 halves the barrier count vs BK=32 and doubles the per-step
// MFMA phase (~160cyc/wave: 8 MFMA + 10 ds_read_b128), covering most of the
// ~200-300cyc L2 load latency with depth-1 prefetch. The asm barrier waits
// lgkmcnt only -- next tile's global loads stay in flight across it; the
// ds_write of the next buffer auto-waits vmcnt after the MFMAs.
// Row pad 72 shorts: 16-lane frag reads alias banks 2-way (free, m136).
// mfma_f32_16x16x32_bf16 D-layout: col=lane&15, row=(lane>>4)*4+reg.
// ---------------------------------------------------------------------------
template<int RELU, int OUTB, int BIAS>
__device__ __forceinline__ void mgemm_body(
    const ushort_t* __restrict__ A, const ushort_t* __restrict__ BT,
    const float* __restrict__ bias, float* __restrict__ Cf,
    ushort_t* __restrict__ Cb, int M, int N, int K, int kBegin, int kSteps)
{
    __shared__ ushort_t Al[2][64][72];
    __shared__ ushort_t Bl[2][64][72];
    const int tid  = threadIdx.x;
    const int m0   = blockIdx.y * 64, n0 = blockIdx.x * 64;
    const int lane = tid & 63, w = tid >> 6;
    const int srow = tid >> 2, sseg = (tid & 3) * 16;
    const int l15  = lane & 15,  kg = (lane >> 4) * 8;

    f32x4 acc0 = {0.f,0.f,0.f,0.f}, acc1 = acc0, acc2 = acc0, acc3 = acc0;

    const ushort_t* Aptr = &A [(size_t)(m0 + srow) * K + kBegin + sseg];
    const ushort_t* Bptr = &BT[(size_t)(n0 + srow) * K + kBegin + sseg];

    // prologue: stage tile 0 into buffer 0
    s16x8 av0 = *(const s16x8*)Aptr,       av1 = *(const s16x8*)(Aptr + 8);
    s16x8 bv0 = *(const s16x8*)Bptr,       bv1 = *(const s16x8*)(Bptr + 8);
    *(s16x8*)&Al[0][srow][sseg]     = av0;
    *(s16x8*)&Al[0][srow][sseg + 8] = av1;
    *(s16x8*)&Bl[0][srow][sseg]     = bv0;
    *(s16x8*)&Bl[0][srow][sseg + 8] = bv1;

    for (int kt = 0; kt < kSteps; ++kt) {
        const int cur = kt & 1;
        const bool more = (kt + 1 < kSteps);
        if (more) {                      // issue next tile's loads (in flight)
            const size_t o = (size_t)(kt + 1) * 64;
            av0 = *(const s16x8*)(Aptr + o);     av1 = *(const s16x8*)(Aptr + o + 8);
            bv0 = *(const s16x8*)(Bptr + o);     bv1 = *(const s16x8*)(Bptr + o + 8);
        }
        // own LDS ops drained; global loads NOT drained (complete under MFMAs)
        asm volatile("s_waitcnt lgkmcnt(0)\n\ts_barrier" ::: "memory");

        s16x8 b0 = *(const s16x8*)&Bl[cur][w * 16 + l15][kg];
        s16x8 b1 = *(const s16x8*)&Bl[cur][w * 16 + l15][kg + 32];
        s16x8 a00 = *(const s16x8*)&Al[cur][     l15][kg];
        s16x8 a01 = *(const s16x8*)&Al[cur][     l15][kg + 32];
        s16x8 a10 = *(const s16x8*)&Al[cur][16 + l15][kg];
        s16x8 a11 = *(const s16x8*)&Al[cur][16 + l15][kg + 32];
        s16x8 a20 = *(const s16x8*)&Al[cur][32 + l15][kg];
        s16x8 a21 = *(const s16x8*)&Al[cur][32 + l15][kg + 32];
        s16x8 a30 = *(const s16x8*)&Al[cur][48 + l15][kg];
        s16x8 a31 = *(const s16x8*)&Al[cur][48 + l15][kg + 32];
        acc0 = __builtin_amdgcn_mfma_f32_16x16x32_bf16(a00, b0, acc0, 0, 0, 0);
        acc1 = __builtin_amdgcn_mfma_f32_16x16x32_bf16(a10, b0, acc1, 0, 0, 0);
        acc2 = __builtin_amdgcn_mfma_f32_16x16x32_bf16(a20, b0, acc2, 0, 0, 0);
        acc3 = __builtin_amdgcn_mfma_f32_16x16x32_bf16(a30, b0, acc3, 0, 0, 0);
        acc0 = __builtin_amdgcn_mfma_f32_16x16x32_bf16(a01, b1, acc0, 0, 0, 0);
        acc1 = __builtin_amdgcn_mfma_f32_16x16x32_bf16(a11, b1, acc1, 0, 0, 0);
        acc2 = __builtin_amdgcn_mfma_f32_16x16x32_bf16(a21, b1, acc2, 0, 0, 0);
        acc3 = __builtin_amdgcn_mfma_f32_16x16x32_bf16(a31, b1, acc3, 0, 0, 0);

        if (more) {                      // auto vmcnt-wait on av/bv here
            *(s16x8*)&Al[cur ^ 1][srow][sseg]     = av0;
            *(s16x8*)&Al[cur ^ 1][srow][sseg + 8] = av1;
            *(s16x8*)&Bl[cur ^ 1][srow][sseg]     = bv0;
            *(s16x8*)&Bl[cur ^ 1][srow][sseg + 8] = bv1;
        }
    }

    const int col = n0 + w * 16 + l15;
    const float bb = BIAS ? bias[col] : 0.f;
    f32x4 accs[4] = {acc0, acc1, acc2, acc3};
#pragma unroll
    for (int r = 0; r < 4; ++r) {
#pragma unroll
        for (int e = 0; e < 4; ++e) {
            const int row = m0 + r * 16 + (lane >> 4) * 4 + e;
            float v = accs[r][e] + bb;
            if (RELU) v = fmaxf(v, 0.f);
            if (OUTB) Cb[(size_t)row * N + col] = f2b(v);
            else      Cf[(size_t)row * N + col] = v;
        }
    }
}

// Split-K: z<2 writes Cf0 + z*M*N ; z>=2 writes Cf1 + (z-2)*M*N (fp32).
template<int RELU, int OUTB, int BIAS>
__global__ __launch_bounds__(256) void mgemm_k(const ushort_t* A, const ushort_t* BT,
    const float* bias, float* Cf0, float* Cf1, ushort_t* Cb,
    int M, int N, int K, int kChunk)
{
    const int z = blockIdx.z;
    float* Cfz = nullptr;
    if (Cf0) Cfz = (z < 2) ? Cf0 + (size_t)z * M * N
                           : Cf1 + (size_t)(z - 2) * M * N;
    mgemm_body<RELU, OUTB, BIAS>(A, BT, bias, Cfz, Cb, M, N, K,
                                 z * kChunk, kChunk / 64);
}

__global__ __launch_bounds__(256) void qkv_k(const ushort_t* Xb, const ushort_t* WT,
    const float* bq, const float* bk, const float* bv,
    ushort_t* Qb, ushort_t* Kb, ushort_t* Vb)
{
    const int z = blockIdx.z;
    const ushort_t* bt = WT + (size_t)z * (D_ * D_);
    const float* bias; ushort_t* out;
    if (z == 0)      { bias = bq; out = Qb; }
    else if (z == 1) { bias = bk; out = Kb; }
    else             { bias = bv; out = Vb; }
    mgemm_body<0, 1, 1>(Xb, bt, bias, nullptr, out, T_, D_, D_, 0, D_ / 64);
}

// ---------------------------------------------------------------------------
// prep: blocks [0,512) = embedding gather (+bf16 X and emb); [512,3072) =
// weight transpose fp32 [R][C] -> bf16 [C][R] in 32x32 LDS tiles.
// ---------------------------------------------------------------------------
__global__ __launch_bounds__(256) void prep_k(const int* __restrict__ xt,
    const float* __restrict__ emb, float* __restrict__ X,
    ushort_t* __restrict__ Xb, ushort_t* __restrict__ embB,
    const float* __restrict__ Wq, const float* __restrict__ Wk,
    const float* __restrict__ Wv, const float* __restrict__ Wo,
    const float* __restrict__ W1, const float* __restrict__ W2,
    ushort_t* __restrict__ WT, ushort_t* __restrict__ W1T, ushort_t* __restrict__ W2T)
{
    __shared__ float Tl[32][33];
    const int tid = threadIdx.x;
    if (blockIdx.x < 512) {
        const int idx = blockIdx.x * 256 + tid;       // < T_*D_ == V_*D_
        const int t = idx >> 8, d = idx & 255;
        const float v = emb[(size_t)xt[t] * D_ + d];
        X[idx]  = v;
        Xb[idx] = f2b(v);
        embB[idx] = f2b(emb[idx]);
        return;
    }
    const int id = blockIdx.x - 512;
    const int l  = id >= 1280 ? 1 : 0;
    const int t  = id - l * 1280;
    const float* src; ushort_t* dst; int R, C, rt, ct;
    if (t < 256) {
        const int kind = t >> 6, tl = t & 63;
        const float* s0 = (kind == 0) ? Wq : (kind == 1) ? Wk : (kind == 2) ? Wv : Wo;
        src = s0 + (size_t)l * (D_ * D_);
        dst = WT + (size_t)l * (4 * D_ * D_) + (size_t)kind * (D_ * D_);
        R = D_; C = D_; rt = tl >> 3; ct = tl & 7;
    } else if (t < 768) {
        const int tl = t - 256;
        src = W1 + (size_t)l * (D_ * FF_); dst = W1T + (size_t)l * (D_ * FF_);
        R = D_; C = FF_; rt = tl >> 6; ct = tl & 63;
    } else {
        const int tl = t - 768;
        src = W2 + (size_t)l * (FF_ * D_); dst = W2T + (size_t)l * (FF_ * D_);
        R = FF_; C = D_; rt = tl >> 3; ct = tl & 7;
    }
    const int r = tid >> 3, c4 = (tid & 7) * 4;
    f32x4 v = *(const f32x4*)&src[(size_t)(rt * 32 + r) * C + ct * 32 + c4];
    Tl[r][c4] = v[0]; Tl[r][c4 + 1] = v[1]; Tl[r][c4 + 2] = v[2]; Tl[r][c4 + 3] = v[3];
    __syncthreads();
    u16x4 ov;
    ov[0] = f2b(Tl[c4 + 0][r]); ov[1] = f2b(Tl[c4 + 1][r]);
    ov[2] = f2b(Tl[c4 + 2][r]); ov[3] = f2b(Tl[c4 + 3][r]);
    *(u16x4*)&dst[(size_t)(ct * 32 + r) * R + rt * 32 + c4] = ov;
}

// ---------------------------------------------------------------------------
// x = LN(x + sum parts + bias) * s + b ; writes fp32 X and bf16 Xb.
// nparts in {1,2,4}: parts 0-1 live in p0[0],p0[TD]; parts 2-3 in p1.
// ---------------------------------------------------------------------------
__global__ __launch_bounds__(256) void add_ln_k(
    const float* __restrict__ p0, const float* __restrict__ p1, int nparts,
    const float* __restrict__ bias, float* __restrict__ X,
    ushort_t* __restrict__ Xb, const float* __restrict__ s,
    const float* __restrict__ b)
{
    __shared__ float red[4];
    const int row = blockIdx.x, tid = threadIdx.x;
    const size_t off = (size_t)row * D_ + tid;
    const size_t TD = (size_t)T_ * D_;
    float a = X[off] + bias[tid] + p0[off];
    if (nparts >= 2) a += p0[TD + off];
    if (nparts == 4) a += p1[off] + p1[TD + off];

    float ws_ = waveReduceSum(a);
    if ((tid & 63) == 0) red[tid >> 6] = ws_;
    __syncthreads();
    const float mean = (red[0] + red[1] + red[2] + red[3]) * (1.f / D_);
    __syncthreads();
    const float d = a - mean;
    float vs = waveReduceSum(d * d);
    if ((tid & 63) == 0) red[tid >> 6] = vs;
    __syncthreads();
    const float var = (red[0] + red[1] + red[2] + red[3]) * (1.f / D_);
    const float y = d * rsqrtf(var + 1e-5f) * s[tid] + b[tid];
    X[off]  = y;
    Xb[off] = f2b(y);
}

// ---------------------------------------------------------------------------
// Fused attention: one block per (b,h,q-quarter). fp32 math, bf16 I/O.
// ---------------------------------------------------------------------------
__global__ __launch_bounds__(256) void attn_k(const ushort_t* __restrict__ Qb,
    const ushort_t* __restrict__ Kb, const ushort_t* __restrict__ Vb,
    ushort_t* __restrict__ Ob)
{
    __shared__ float Qs[32][36], Ks[128][36], Vs[128][36], Ps[32][132];
    const int bh = blockIdx.x, b = bh >> 3, h = bh & 7;
    const int i0 = blockIdx.y * 32;
    const int tid = threadIdx.x;

#pragma unroll
    for (int it = 0; it < 2; ++it) {                 // K,V: 512 8-elem chunks
        const int g = it * 256 + tid;
        const int r = g >> 2, c8 = (g & 3) * 8;
        s16x8 kv = *(const s16x8*)&Kb[(size_t)(b * S_ + r) * D_ + h * DH_ + c8];
        s16x8 vv = *(const s16x8*)&Vb[(size_t)(b * S_ + r) * D_ + h * DH_ + c8];
        f32x4 klo = {b2f((ushort_t)kv[0]), b2f((ushort_t)kv[1]), b2f((ushort_t)kv[2]), b2f((ushort_t)kv[3])};
        f32x4 khi = {b2f((ushort_t)kv[4]), b2f((ushort_t)kv[5]), b2f((ushort_t)kv[6]), b2f((ushort_t)kv[7])};
        f32x4 vlo = {b2f((ushort_t)vv[0]), b2f((ushort_t)vv[1]), b2f((ushort_t)vv[2]), b2f((ushort_t)vv[3])};
        f32x4 vhi = {b2f((ushort_t)vv[4]), b2f((ushort_t)vv[5]), b2f((ushort_t)vv[6]), b2f((ushort_t)vv[7])};
        *(f32x4*)&Ks[r][c8]     = klo;  *(f32x4*)&Ks[r][c8 + 4] = khi;
        *(f32x4*)&Vs[r][c8]     = vlo;  *(f32x4*)&Vs[r][c8 + 4] = vhi;
    }
    if (tid < 128) {                                  // Q: 128 chunks
        const int r = tid >> 2, c8 = (tid & 3) * 8;
        s16x8 qv = *(const s16x8*)&Qb[(size_t)(b * S_ + i0 + r) * D_ + h * DH_ + c8];
        f32x4 qlo = {b2f((ushort_t)qv[0]), b2f((ushort_t)qv[1]), b2f((ushort_t)qv[2]), b2f((ushort_t)qv[3])};
        f32x4 qhi = {b2f((ushort_t)qv[4]), b2f((ushort_t)qv[5]), b2f((ushort_t)qv[6]), b2f((ushort_t)qv[7])};
        *(f32x4*)&Qs[r][c8] = qlo;  *(f32x4*)&Qs[r][c8 + 4] = qhi;
    }
    __syncthreads();

    const int i = tid >> 3, jg = tid & 7;
    const float sc = 0.17677669529663687f;   // 1/sqrt(32)
    float sv[16];
    float mx = -1e30f;
#pragma unroll
    for (int jj = 0; jj < 16; ++jj) {
        const int j = jg + jj * 8;
        f32x4 a4 = {0.f,0.f,0.f,0.f};
#pragma unroll
        for (int kk = 0; kk < 8; ++kk) {
            f32x4 q = *(const f32x4*)&Qs[i][kk * 4];
            f32x4 k = *(const f32x4*)&Ks[j][kk * 4];
            a4 += q * k;
        }
        const float sdot = (a4[0] + a4[1] + a4[2] + a4[3]) * sc;
        sv[jj] = sdot;
        mx = fmaxf(mx, sdot);
    }
    mx = fmaxf(mx, __shfl_xor(mx, 1));
    mx = fmaxf(mx, __shfl_xor(mx, 2));
    mx = fmaxf(mx, __shfl_xor(mx, 4));
    float sum = 0.f;
#pragma unroll
    for (int jj = 0; jj < 16; ++jj) {
        const float e = __expf(sv[jj] - mx);
        Ps[i][jg + jj * 8] = e;
        sum += e;
    }
    sum += __shfl_xor(sum, 1);
    sum += __shfl_xor(sum, 2);
    sum += __shfl_xor(sum, 4);
    const float inv = 1.f / sum;
    __syncthreads();

    const int dg = tid & 7;
    f32x4 o = {0.f,0.f,0.f,0.f};
#pragma unroll 4
    for (int j = 0; j < 128; ++j) {
        const float p = Ps[i][j];
        f32x4 vv = *(const f32x4*)&Vs[j][dg * 4];
        o += vv * p;
    }
    u16x4 ov;
    ov[0] = f2b(o[0] * inv); ov[1] = f2b(o[1] * inv);
    ov[2] = f2b(o[2] * inv); ov[3] = f2b(o[3] * inv);
    *(u16x4*)&Ob[(size_t)(b * S_ + i0 + i) * D_ + h * DH_ + dg * 4] = ov;
}

// ---------------------------------------------------------------------------
// Fused final softmax + broadcast: block = (token t, quarter of row-range).
// Each block re-computes softmax(t) (cheap, 4x redundant) then streams 128
// rows of 2KB with nontemporal float4 stores.
// ---------------------------------------------------------------------------
__global__ __launch_bounds__(256) void bcast_k(const float* __restrict__ Lg,
    const float* __restrict__ temp, float* __restrict__ out)
{
    __shared__ float row[V_];
    __shared__ float red[4];
    const int blk = blockIdx.x, t = blk >> 2, quarter = blk & 3;
    const int tid = threadIdx.x;
    const float rT = 1.f / temp[0];
    const float l0 = Lg[(size_t)t * V_ + tid] * rT;
    const float l1 = Lg[(size_t)t * V_ + 256 + tid] * rT;
    float m = waveReduceMax(fmaxf(l0, l1));
    if ((tid & 63) == 0) red[tid >> 6] = m;
    __syncthreads();
    m = fmaxf(fmaxf(red[0], red[1]), fmaxf(red[2], red[3]));
    __syncthreads();
    const float e0 = __expf(l0 - m), e1 = __expf(l1 - m);
    float sblk = waveReduceSum(e0 + e1);
    if ((tid & 63) == 0) red[tid >> 6] = sblk;
    __syncthreads();
    const float inv = 1.f / (red[0] + red[1] + red[2] + red[3]);
    row[tid] = e0 * inv;
    row[tid + 256] = e1 * inv;
    __syncthreads();

    const int c = tid & 127, ihalf = tid >> 7;
    f32x4 v = *(const f32x4*)&row[c * 4];
    f32x4* dst = (f32x4*)out + (size_t)t * V_ * (V_ / 4);
#pragma unroll 4
    for (int r = 0; r < 64; ++r) {
        const int i = quarter * 128 + ihalf + r * 2;
        __builtin_nontemporal_store(v, &dst[(size_t)i * (V_ / 4) + c]);
    }
}

// ---------------------------------------------------------------------------
// Host launch. ws layout (bytes), total 10.0 MB:
//   0        X     fp32 512KB
//   524288   PartA fp32 2x512KB (split-K parts 0-1; alias Lg 1MB at end)
//   1572864  Qb    bf16 256KB  \
//   1835008  Kb    bf16 256KB   } parts 2-3 alias this 1MB during W2 GEMM
//   2097152  Vb    bf16 256KB   } (Qb..Ob dead at that point in the layer)
//   2359296  Ob    bf16 256KB  /
//   2621440  Xb    bf16 256KB
//   2883584  Ffb   bf16 2MB
//   4980736  embB  bf16 256KB
//   5242880  WT    bf16 1MB
//   6291456  W1T   bf16 2MB
//   8388608  W2T   bf16 2MB   -> end 10485760
// ---------------------------------------------------------------------------
extern "C" void kernel_launch(void* const* d_in, const int* in_sizes, int n_in,
                              void* d_out, int out_size, void* d_ws, size_t ws_size,
                              hipStream_t stream)
{
    const int*   x_t  = (const int*)  d_in[0];
    const float* emb  = (const float*)d_in[1];
    const float* temp = (const float*)d_in[2];
    const float* Wq   = (const float*)d_in[3];
    const float* Wk   = (const float*)d_in[4];
    const float* Wv   = (const float*)d_in[5];
    const float* Wo   = (const float*)d_in[6];
    const float* bq   = (const float*)d_in[7];
    const float* bk   = (const float*)d_in[8];
    const float* bv   = (const float*)d_in[9];
    const float* bo   = (const float*)d_in[10];
    const float* W1   = (const float*)d_in[11];
    const float* b1   = (const float*)d_in[12];
    const float* W2   = (const float*)d_in[13];
    const float* b2   = (const float*)d_in[14];
    const float* ln1s = (const float*)d_in[15];
    const float* ln1b = (const float*)d_in[16];
    const float* ln2s = (const float*)d_in[17];
    const float* ln2b = (const float*)d_in[18];

    float* out = (float*)d_out;
    char*  wsb = (char*)d_ws;

    float*    X     = (float*)   (wsb + 0);
    float*    PartA = (float*)   (wsb + 524288);
    float*    Lg    = PartA;                        // alias (disjoint lifetime)
    ushort_t* Qb    = (ushort_t*)(wsb + 1572864);
    float*    PartB = (float*)   (wsb + 1572864);   // alias Qb..Ob (parts 2-3)
    ushort_t* Kb    = (ushort_t*)(wsb + 1835008);
    ushort_t* Vb    = (ushort_t*)(wsb + 2097152);
    ushort_t* Ob    = (ushort_t*)(wsb + 2359296);
    ushort_t* Xb    = (ushort_t*)(wsb + 2621440);
    ushort_t* Ffb   = (ushort_t*)(wsb + 2883584);
    ushort_t* embB  = (ushort_t*)(wsb + 4980736);
    ushort_t* WT    = (ushort_t*)(wsb + 5242880);
    ushort_t* W1T   = (ushort_t*)(wsb + 6291456);
    ushort_t* W2T   = (ushort_t*)(wsb + 8388608);

    prep_k<<<3072, 256, 0, stream>>>(x_t, emb, X, Xb, embB,
                                     Wq, Wk, Wv, Wo, W1, W2, WT, W1T, W2T);

    for (int l = 0; l < L_; ++l) {
        const ushort_t* WTl  = WT  + (size_t)l * (4 * D_ * D_);
        const ushort_t* W1Tl = W1T + (size_t)l * (D_ * FF_);
        const ushort_t* W2Tl = W2T + (size_t)l * (FF_ * D_);

        qkv_k<<<dim3(4, 8, 3), 256, 0, stream>>>(
            Xb, WTl, bq + l * D_, bk + l * D_, bv + l * D_, Qb, Kb, Vb);

        attn_k<<<dim3(32, 4), 256, 0, stream>>>(Qb, Kb, Vb, Ob);

        // o @ Wo split-K z=2 -> PartA[0..1]; bias bo folded into add_ln
        mgemm_k<0, 0, 0><<<dim3(4, 8, 2), 256, 0, stream>>>(
            Ob, WTl + 3 * D_ * D_, nullptr, PartA, nullptr, nullptr,
            T_, D_, D_, D_ / 2);
        add_ln_k<<<T_, 256, 0, stream>>>(PartA, nullptr, 2, bo + l * D_,
                                         X, Xb, ln1s + l * D_, ln1b + l * D_);

        // relu(x @ W1 + b1) -> Ffb (bf16)
        mgemm_k<1, 1, 1><<<dim3(32, 8, 1), 256, 0, stream>>>(
            Xb, W1Tl, b1 + l * FF_, nullptr, nullptr, Ffb, T_, FF_, D_, D_);

        // Ffb @ W2 split-K z=4 -> PartA[0..1] + PartB[0..1]; b2 in add_ln
        mgemm_k<0, 0, 0><<<dim3(4, 8, 4), 256, 0, stream>>>(
            Ffb, W2Tl, nullptr, PartA, PartB, nullptr, T_, D_, FF_, FF_ / 4);
        add_ln_k<<<T_, 256, 0, stream>>>(PartA, PartB, 4, b2 + l * D_,
                                         X, Xb, ln2s + l * D_, ln2b + l * D_);
    }

    // logits = Xb @ embB^T -> Lg (fp32)
    mgemm_k<0, 0, 0><<<dim3(8, 8, 1), 256, 0, stream>>>(
        Xb, embB, nullptr, Lg, nullptr, nullptr, T_, V_, D_, D_);

    bcast_k<<<T_ * 4, 256, 0, stream>>>(Lg, temp, out);
}